// Round 9
// baseline (272.809 us; speedup 1.0000x reference)
//
#include <hip/hip_runtime.h>
#include <math.h>

static constexpr int N   = 3072;
static constexpr int DIN = 64;
static constexpr int D   = 128;
static constexpr int H   = 4;
static constexpr int E   = 49152;
#define NEGV  (-4294967295.0f)
#define SCALE (0.08838834764831845f)   // 1/sqrt(128)

typedef unsigned short u16;
typedef __attribute__((ext_vector_type(8))) short short8;
typedef __attribute__((ext_vector_type(4))) float f32x4;
typedef __attribute__((ext_vector_type(4))) unsigned short u16x4;

__device__ __forceinline__ u16 f2bf(float f){           // RNE float->bf16
  unsigned int u = __float_as_uint(f);
  u += 0x7fff + ((u >> 16) & 1);
  return (u16)(u >> 16);
}
__device__ __forceinline__ float bf2f(u16 u){
  return __uint_as_float(((unsigned int)u) << 16);
}

// ---------------------------------------------------------------- deg
__global__ void k_zero_deg(int* __restrict__ deg){
  int i = blockIdx.x*blockDim.x + threadIdx.x;
  if(i < N) deg[i] = 0;
}

__global__ void k_deg(const int* __restrict__ ei, int* __restrict__ deg){
  int e = blockIdx.x*blockDim.x + threadIdx.x;
  if(e < E) atomicAdd(&deg[ei[E + e]], 1);
}

// ---------------------------------------------------------------- h0 + fused LN1(layer0)
__global__ void k_h0(const float* __restrict__ x, const float* __restrict__ nodeW,
                     const float* __restrict__ nodeb, const float* __restrict__ degemb,
                     const int* __restrict__ deg, const float* __restrict__ g1,
                     const float* __restrict__ b1, float* __restrict__ mask,
                     float* __restrict__ h, float* __restrict__ xln){
  const int i = blockIdx.x, t = threadIdx.x;
  float xv = x[i*DIN + t];
  float s = xv;
  #pragma unroll
  for(int o=32;o;o>>=1) s += __shfl_xor(s, o);
  if(t == 0) mask[i] = (s != 0.0f) ? 1.0f : 0.0f;
  __shared__ float xr[DIN];
  xr[t] = xv;
  __syncthreads();
  int dg = deg[i]; dg = dg > N-1 ? N-1 : dg;
  float a0 = nodeb[t]      + degemb[dg*D + t];
  float a1 = nodeb[t + 64] + degemb[dg*D + t + 64];
  #pragma unroll
  for(int u=0; u<DIN; ++u){
    float xu = xr[u];
    a0 = fmaf(xu, nodeW[u*D + t],      a0);
    a1 = fmaf(xu, nodeW[u*D + t + 64], a1);
  }
  h[i*D + t]      = a0;
  h[i*D + t + 64] = a1;
  float s2 = a0 + a1, sq = a0*a0 + a1*a1;
  #pragma unroll
  for(int o=32;o;o>>=1){ s2 += __shfl_xor(s2, o); sq += __shfl_xor(sq, o); }
  float mean = s2*(1.0f/128.0f);
  float var  = sq*(1.0f/128.0f) - mean*mean;
  float inv  = rsqrtf(var + 1e-5f);
  xln[i*D + t]      = (a0 - mean)*inv*g1[t]      + b1[t];
  xln[i*D + t + 64] = (a1 - mean)*inv*g1[t + 64] + b1[t + 64];
}

// ---------------------------------------------------------------- bias (masked, bf16)
__global__ void k_bias(const int* __restrict__ spl, const float* __restrict__ ef,
                       const float* __restrict__ spe, const float* __restrict__ eW,
                       const float* __restrict__ eb, const float* __restrict__ mask,
                       u16* __restrict__ biasm){
  int idx = blockIdx.x*blockDim.x + threadIdx.x;   // < N*N
  int i = idx / N, j = idx % N;
  float wm0 = (eW[0] + eW[1] + eW[2] + eW[3])  * 0.25f;
  float wm1 = (eW[4] + eW[5] + eW[6] + eW[7])  * 0.25f;
  float wm2 = (eW[8] + eW[9] + eW[10]+ eW[11]) * 0.25f;
  float wm3 = (eW[12]+ eW[13]+ eW[14]+ eW[15]) * 0.25f;
  float bm  = (eb[0] + eb[1] + eb[2] + eb[3])  * 0.25f;
  float4 e4 = reinterpret_cast<const float4*>(ef)[idx];
  float em = fmaf(e4.x, wm0, fmaf(e4.y, wm1, fmaf(e4.z, wm2, fmaf(e4.w, wm3, bm))));
  float b = spe[spl[idx]] + em;
  float mk = mask[i]*mask[j];
  biasm[idx] = f2bf((mk != 0.0f) ? b : NEGV);
}

// ---------------------------------------------------------------- weight prep: fp32 [K][128] -> bf16 Bt [128][K]
__global__ __launch_bounds__(256) void k_wt_all(const float* __restrict__ Wq, const float* __restrict__ Wk,
    const float* __restrict__ Wv, const float* __restrict__ ffW, const float* __restrict__ outW,
    u16* __restrict__ wt_qkv, u16* __restrict__ wt_ff, u16* __restrict__ wt_out){
  __shared__ float t[32][33];
  const int z = blockIdx.y;
  const float* src; u16* dst;
  if(z < 24){
    int l = z/12, r = z%12;
    const float* W = (r>>2)==0 ? Wq : (r>>2)==1 ? Wk : Wv;
    src = W + (size_t)(l*4 + (r&3))*16384;
    dst = wt_qkv + (size_t)z*16384;
  } else if(z < 26){
    src = ffW + (size_t)(z-24)*16384; dst = wt_ff + (size_t)(z-24)*16384;
  } else { src = outW; dst = wt_out; }
  const int ki = blockIdx.x & 3, ni = blockIdx.x >> 2;
  const int tid = threadIdx.x;
  #pragma unroll
  for(int i=0;i<4;i++){
    int idx = tid + i*256, r = idx>>5, c = idx&31;
    t[r][c] = src[(size_t)(ki*32+r)*128 + ni*32 + c];
  }
  __syncthreads();
  #pragma unroll
  for(int i=0;i<4;i++){
    int idx = tid + i*256, r = idx>>5, c = idx&31;
    dst[(size_t)(ni*32+r)*128 + ki*32 + c] = f2bf(t[c][r]);
  }
}

__global__ __launch_bounds__(256) void k_wt_wo(const float* __restrict__ Wo, u16* __restrict__ wt_wo){
  __shared__ float t[32][33];
  const int l = blockIdx.y;
  const float* src = Wo + (size_t)l*65536;
  u16* dst = wt_wo + (size_t)l*65536;
  const int ki = blockIdx.x & 15, ni = blockIdx.x >> 4;
  const int tid = threadIdx.x;
  #pragma unroll
  for(int i=0;i<4;i++){
    int idx = tid + i*256, r = idx>>5, c = idx&31;
    t[r][c] = src[(size_t)(ki*32+r)*128 + ni*32 + c];
  }
  __syncthreads();
  #pragma unroll
  for(int i=0;i<4;i++){
    int idx = tid + i*256, r = idx>>5, c = idx&31;
    dst[(size_t)(ni*32+r)*512 + ki*32 + c] = f2bf(t[c][r]);
  }
}

// ---------------------------------------------------------------- bf16 MFMA GEMM (K=128), C = A@Bt^T + bias
// MODE: 0 = fp32 row-major, 1 = bf16 row-major, 2 = bf16 transposed (vT[d][n], coalesced via LDS)
template<int MODE>
__device__ __forceinline__ void mgemm_body(const float* __restrict__ A, const u16* __restrict__ Bt,
                                           const float* __restrict__ bias, void* __restrict__ Cv){
  __shared__ u16 As[64*128];
  __shared__ u16 Bs[128*128];
  const int tid = threadIdx.x, w = tid>>6, lane = tid&63;
  const int g4 = lane>>4, l16 = lane&15;
  const int m0 = blockIdx.x*64;
  const int srow = tid>>4, sch = tid&15;
  f32x4 acc[8];
  #pragma unroll
  for(int nt=0;nt<8;++nt) acc[nt] = (f32x4){0.f,0.f,0.f,0.f};
  #pragma unroll
  for(int it=0;it<4;++it){
    int row = it*16 + srow;
    const float4* ap = reinterpret_cast<const float4*>(A + (size_t)(m0+row)*128 + sch*8);
    float4 x0 = ap[0], x1 = ap[1];
    u16x4 p0, p1;
    p0.x=f2bf(x0.x); p0.y=f2bf(x0.y); p0.z=f2bf(x0.z); p0.w=f2bf(x0.w);
    p1.x=f2bf(x1.x); p1.y=f2bf(x1.y); p1.z=f2bf(x1.z); p1.w=f2bf(x1.w);
    u16* dst = &As[row*128 + ((sch ^ (row&15))*8)];
    *reinterpret_cast<u16x4*>(dst)     = p0;
    *reinterpret_cast<u16x4*>(dst + 4) = p1;
  }
  #pragma unroll
  for(int it=0;it<8;++it){
    int row = it*16 + srow;
    short8 b = *reinterpret_cast<const short8*>(Bt + (size_t)row*128 + sch*8);
    *reinterpret_cast<short8*>(&Bs[row*128 + ((sch ^ (row&15))*8)]) = b;
  }
  __syncthreads();
  __builtin_amdgcn_s_setprio(1);
  #pragma unroll
  for(int c=0;c<4;++c){
    short8 af = *reinterpret_cast<const short8*>(&As[(w*16+l16)*128 + (((c*4+g4) ^ l16)*8)]);
    #pragma unroll
    for(int nt=0;nt<8;++nt){
      short8 bf = *reinterpret_cast<const short8*>(&Bs[(nt*16+l16)*128 + (((c*4+g4) ^ l16)*8)]);
      acc[nt] = __builtin_amdgcn_mfma_f32_16x16x32_bf16(af, bf, acc[nt], 0, 0, 0);
    }
  }
  __builtin_amdgcn_s_setprio(0);
  const int mrow = m0 + w*16 + g4*4;
  if(MODE == 2){
    __syncthreads();
    u16* T = Bs;                                   // [col][64 rows], stride 68
    #pragma unroll
    for(int nt=0;nt<8;++nt){
      const int col = nt*16 + l16;
      float bi = bias[col];
      u16x4 t;
      t.x = f2bf(acc[nt][0] + bi); t.y = f2bf(acc[nt][1] + bi);
      t.z = f2bf(acc[nt][2] + bi); t.w = f2bf(acc[nt][3] + bi);
      *reinterpret_cast<u16x4*>(&T[col*68 + (w*16 + g4*4)]) = t;
    }
    __syncthreads();
    #pragma unroll
    for(int i=0;i<4;++i){
      int slot = tid + i*256;
      int col = slot >> 3, q = slot & 7;
      short8 v = *reinterpret_cast<const short8*>(&T[col*68 + q*8]);
      *reinterpret_cast<short8*>((u16*)Cv + (size_t)col*N + m0 + q*8) = v;
    }
  } else {
    #pragma unroll
    for(int nt=0;nt<8;++nt){
      const int col = nt*16 + l16;
      float bi = bias[col];
      #pragma unroll
      for(int rg=0;rg<4;++rg){
        float v = acc[nt][rg] + bi;
        if(MODE == 1) ((u16*)Cv)[(size_t)(mrow+rg)*128 + col] = f2bf(v);
        else          ((float*)Cv)[(size_t)(mrow+rg)*128 + col] = v;
      }
    }
  }
}

// grid (N/64, 12): z = which*4 + head. V written directly transposed (vT[h][d][n]).
__global__ __launch_bounds__(256) void k_mqkv(const float* __restrict__ xln, const u16* __restrict__ wt_qkv,
    const float* __restrict__ bq, const float* __restrict__ bk, const float* __restrict__ bv,
    u16* __restrict__ q, u16* __restrict__ k, u16* __restrict__ vT, int l){
  const int z = blockIdx.y, which = z>>2, head = z&3;
  const u16* Bt = wt_qkv + (size_t)(l*12 + z)*16384;
  if(which == 0)      mgemm_body<1>(xln, Bt, bq + (l*H+head)*D, q  + (size_t)head*N*D);
  else if(which == 1) mgemm_body<1>(xln, Bt, bk + (l*H+head)*D, k  + (size_t)head*N*D);
  else                mgemm_body<2>(xln, Bt, bv + (l*H+head)*D, vT + (size_t)head*N*D);
}

__global__ __launch_bounds__(256) void k_mout(const float* __restrict__ h, const u16* __restrict__ wt_out,
    const float* __restrict__ outb, float* __restrict__ out){
  mgemm_body<0>(h, wt_out, outb, out);
}

// ---------------------------------------------------------------- Wo GEMM, fused split-K combine (staging) + LN2 (epilogue)
template<int S>
__global__ __launch_bounds__(256) void k_mwo(const float* __restrict__ opart, const float* __restrict__ mpart,
    const float* __restrict__ lpart, const float* __restrict__ mask, const u16* __restrict__ wt,
    const float* __restrict__ bo, const float* __restrict__ hres,
    float* __restrict__ xout, float* __restrict__ xln,
    const float* __restrict__ g2, const float* __restrict__ b2){
  __shared__ u16 As[64*128];
  __shared__ u16 Bs[128*128];
  const int tid = threadIdx.x, w = tid>>6, lane = tid&63;
  const int g4 = lane>>4, l16 = lane&15;
  const int m0 = blockIdx.x*64;
  const int srow = tid>>4, sch = tid&15;
  f32x4 acc[8];
  #pragma unroll
  for(int nt=0;nt<8;++nt) acc[nt] = (f32x4){0.f,0.f,0.f,0.f};
  for(int k0 = 0; k0 < 512; k0 += 128){
    const int hh = k0 >> 7;
    __syncthreads();
    #pragma unroll
    for(int it=0;it<4;++it){
      int row = it*16 + srow;
      int grow = m0 + row;
      float w_[S]; float M = -INFINITY; float mv[S], lv[S];
      #pragma unroll
      for(int s=0;s<S;++s){
        mv[s] = mpart[(size_t)(s*H + hh)*N + grow];
        lv[s] = lpart[(size_t)(s*H + hh)*N + grow];
        M = fmaxf(M, mv[s]);
      }
      float denom = 0.f;
      #pragma unroll
      for(int s=0;s<S;++s){ w_[s] = __expf(mv[s] - M); denom = fmaf(lv[s], w_[s], denom); }
      float scale = mask[grow] / denom;
      const int d = sch*8;
      float4 v0 = make_float4(0,0,0,0), v1 = make_float4(0,0,0,0);
      #pragma unroll
      for(int s=0;s<S;++s){
        const float4* op = reinterpret_cast<const float4*>(
            opart + ((size_t)(s*H + hh)*N + grow)*D + d);
        float4 a = op[0], b = op[1];
        v0.x = fmaf(a.x, w_[s], v0.x); v0.y = fmaf(a.y, w_[s], v0.y);
        v0.z = fmaf(a.z, w_[s], v0.z); v0.w = fmaf(a.w, w_[s], v0.w);
        v1.x = fmaf(b.x, w_[s], v1.x); v1.y = fmaf(b.y, w_[s], v1.y);
        v1.z = fmaf(b.z, w_[s], v1.z); v1.w = fmaf(b.w, w_[s], v1.w);
      }
      u16x4 p0, p1;
      p0.x=f2bf(v0.x*scale); p0.y=f2bf(v0.y*scale); p0.z=f2bf(v0.z*scale); p0.w=f2bf(v0.w*scale);
      p1.x=f2bf(v1.x*scale); p1.y=f2bf(v1.y*scale); p1.z=f2bf(v1.z*scale); p1.w=f2bf(v1.w*scale);
      u16* dst = &As[row*128 + ((sch ^ (row&15))*8)];
      *reinterpret_cast<u16x4*>(dst)     = p0;
      *reinterpret_cast<u16x4*>(dst + 4) = p1;
    }
    #pragma unroll
    for(int it=0;it<8;++it){
      int row = it*16 + srow;
      short8 b = *reinterpret_cast<const short8*>(wt + (size_t)row*512 + k0 + sch*8);
      *reinterpret_cast<short8*>(&Bs[row*128 + ((sch ^ (row&15))*8)]) = b;
    }
    __syncthreads();
    __builtin_amdgcn_s_setprio(1);
    #pragma unroll
    for(int c=0;c<4;++c){
      short8 af = *reinterpret_cast<const short8*>(&As[(w*16+l16)*128 + (((c*4+g4) ^ l16)*8)]);
      #pragma unroll
      for(int nt=0;nt<8;++nt){
        short8 bf = *reinterpret_cast<const short8*>(&Bs[(nt*16+l16)*128 + (((c*4+g4) ^ l16)*8)]);
        acc[nt] = __builtin_amdgcn_mfma_f32_16x16x32_bf16(af, bf, acc[nt], 0, 0, 0);
      }
    }
    __builtin_amdgcn_s_setprio(0);
  }
  const int mrow = m0 + w*16 + g4*4;
  float s_[4] = {0,0,0,0}, q_[4] = {0,0,0,0};
  #pragma unroll
  for(int nt=0;nt<8;++nt){
    const int col = nt*16 + l16;
    float bi = bo[col];
    #pragma unroll
    for(int rg=0;rg<4;++rg){
      float v = acc[nt][rg] + bi + hres[(size_t)(mrow+rg)*128 + col];
      acc[nt][rg] = v;
      s_[rg] += v; q_[rg] = fmaf(v, v, q_[rg]);
    }
  }
  #pragma unroll
  for(int o=1;o<16;o<<=1){
    #pragma unroll
    for(int rg=0;rg<4;++rg){ s_[rg] += __shfl_xor(s_[rg], o); q_[rg] += __shfl_xor(q_[rg], o); }
  }
  float mean[4], inv[4];
  #pragma unroll
  for(int rg=0;rg<4;++rg){
    mean[rg] = s_[rg]*(1.0f/128.0f);
    float var = q_[rg]*(1.0f/128.0f) - mean[rg]*mean[rg];
    inv[rg] = rsqrtf(var + 1e-5f);
  }
  #pragma unroll
  for(int nt=0;nt<8;++nt){
    const int col = nt*16 + l16;
    float gg = g2[col], bb = b2[col];
    #pragma unroll
    for(int rg=0;rg<4;++rg){
      float v = acc[nt][rg];
      xout[(size_t)(mrow+rg)*128 + col] = v;
      xln [(size_t)(mrow+rg)*128 + col] = (v - mean[rg])*inv[rg]*gg + bb;
    }
  }
}

// ---------------------------------------------------------------- FF GEMM + residual, fused LN1(l+1) epilogue
__global__ __launch_bounds__(256) void k_mff(const float* __restrict__ xlnin, const u16* __restrict__ wt,
    const float* __restrict__ ffb, const float* __restrict__ res, float* __restrict__ hout,
    float* __restrict__ xlnout, const float* __restrict__ g1n, const float* __restrict__ b1n,
    int write_ln){
  __shared__ u16 As[64*128];
  __shared__ u16 Bs[128*128];
  const int tid = threadIdx.x, w = tid>>6, lane = tid&63;
  const int g4 = lane>>4, l16 = lane&15;
  const int m0 = blockIdx.x*64;
  const int srow = tid>>4, sch = tid&15;
  f32x4 acc[8];
  #pragma unroll
  for(int nt=0;nt<8;++nt) acc[nt] = (f32x4){0.f,0.f,0.f,0.f};
  #pragma unroll
  for(int it=0;it<4;++it){
    int row = it*16 + srow;
    const float4* ap = reinterpret_cast<const float4*>(xlnin + (size_t)(m0+row)*128 + sch*8);
    float4 x0 = ap[0], x1 = ap[1];
    u16x4 p0, p1;
    p0.x=f2bf(x0.x); p0.y=f2bf(x0.y); p0.z=f2bf(x0.z); p0.w=f2bf(x0.w);
    p1.x=f2bf(x1.x); p1.y=f2bf(x1.y); p1.z=f2bf(x1.z); p1.w=f2bf(x1.w);
    u16* dst = &As[row*128 + ((sch ^ (row&15))*8)];
    *reinterpret_cast<u16x4*>(dst)     = p0;
    *reinterpret_cast<u16x4*>(dst + 4) = p1;
  }
  #pragma unroll
  for(int it=0;it<8;++it){
    int row = it*16 + srow;
    short8 b = *reinterpret_cast<const short8*>(wt + (size_t)row*128 + sch*8);
    *reinterpret_cast<short8*>(&Bs[row*128 + ((sch ^ (row&15))*8)]) = b;
  }
  __syncthreads();
  __builtin_amdgcn_s_setprio(1);
  #pragma unroll
  for(int c=0;c<4;++c){
    short8 af = *reinterpret_cast<const short8*>(&As[(w*16+l16)*128 + (((c*4+g4) ^ l16)*8)]);
    #pragma unroll
    for(int nt=0;nt<8;++nt){
      short8 bf = *reinterpret_cast<const short8*>(&Bs[(nt*16+l16)*128 + (((c*4+g4) ^ l16)*8)]);
      acc[nt] = __builtin_amdgcn_mfma_f32_16x16x32_bf16(af, bf, acc[nt], 0, 0, 0);
    }
  }
  __builtin_amdgcn_s_setprio(0);
  const int mrow = m0 + w*16 + g4*4;
  float s_[4] = {0,0,0,0}, q_[4] = {0,0,0,0};
  #pragma unroll
  for(int nt=0;nt<8;++nt){
    const int col = nt*16 + l16;
    float bi = ffb[col];
    #pragma unroll
    for(int rg=0;rg<4;++rg){
      float v = acc[nt][rg] + bi + res[(size_t)(mrow+rg)*128 + col];
      acc[nt][rg] = v;
      s_[rg] += v; q_[rg] = fmaf(v, v, q_[rg]);
    }
  }
  #pragma unroll
  for(int nt=0;nt<8;++nt){
    const int col = nt*16 + l16;
    #pragma unroll
    for(int rg=0;rg<4;++rg)
      hout[(size_t)(mrow+rg)*128 + col] = acc[nt][rg];
  }
  if(write_ln){
    #pragma unroll
    for(int o=1;o<16;o<<=1){
      #pragma unroll
      for(int rg=0;rg<4;++rg){ s_[rg] += __shfl_xor(s_[rg], o); q_[rg] += __shfl_xor(q_[rg], o); }
    }
    #pragma unroll
    for(int rg=0;rg<4;++rg){
      float mean = s_[rg]*(1.0f/128.0f);
      float var  = q_[rg]*(1.0f/128.0f) - mean*mean;
      float inv  = rsqrtf(var + 1e-5f);
      s_[rg] = mean; q_[rg] = inv;
    }
    #pragma unroll
    for(int nt=0;nt<8;++nt){
      const int col = nt*16 + l16;
      float gg = g1n[col], bb = b1n[col];
      #pragma unroll
      for(int rg=0;rg<4;++rg)
        xlnout[(size_t)(mrow+rg)*128 + col] = (acc[nt][rg] - s_[rg])*q_[rg]*gg + bb;
    }
  }
}

// ---------------------------------------------------------------- MFMA flash attention, QBLK=32/wave
// Block = 256 thr (4 waves), 128 q-rows (32/wave, two 16-row groups); grid (N/128, H, SPLIT).
// Same verified fragment layouts as before; K/V LDS fragment reads amortized over 2 q-groups.
__global__ __launch_bounds__(256) void k_attn(const u16* __restrict__ q, const u16* __restrict__ k,
                     const u16* __restrict__ vT, const u16* __restrict__ biasm,
                     float* __restrict__ opart, float* __restrict__ mpart, float* __restrict__ lpart,
                     int kvlen){
  const int tid  = threadIdx.x;
  const int w    = tid >> 6;
  const int lane = tid & 63;
  const int g4 = lane >> 4, l16 = lane & 15;
  const int head = blockIdx.y, sp = blockIdx.z;
  const int r0 = blockIdx.x*128 + w*32;
  __shared__ u16 Ks[64*128];          // [key][128 dims], swizzled
  __shared__ u16 Vs[64*128];          // [d&63][seg | 64 keys], swizzled
  __shared__ u16 P[4][2][16][40];     // per-wave, per-group

  const u16* qbase = q + ((size_t)head*N + r0)*D;
  short8 qf0[4], qf1[4];
  #pragma unroll
  for(int c=0;c<4;c++){
    qf0[c] = *reinterpret_cast<const short8*>(qbase + l16*D + c*32 + g4*8);
    qf1[c] = *reinterpret_cast<const short8*>(qbase + (16+l16)*D + c*32 + g4*8);
  }

  f32x4 o0[8], o1[8];
  #pragma unroll
  for(int dt=0;dt<8;dt++){ o0[dt] = (f32x4){0.f,0.f,0.f,0.f}; o1[dt] = o0[dt]; }
  float m0v = -INFINITY, ls0 = 0.0f;
  float m1v = -INFINITY, ls1 = 0.0f;

  const u16* kh   = k  + (size_t)head*N*D;
  const u16* vTh  = vT + (size_t)head*D*N;
  const u16* brow0 = biasm + (size_t)(r0 + l16)*N;
  const u16* brow1 = biasm + (size_t)(r0 + 16 + l16)*N;
  const int kv0 = sp*kvlen;

  const int krow = tid >> 4, kch = tid & 15;
  const int vrow = tid >> 3, vch = tid & 7;

  for(int j0 = kv0; j0 < kv0 + kvlen; j0 += 64){
    short8 kreg[4], vreg[4];
    #pragma unroll
    for(int it=0; it<4; ++it)
      kreg[it] = *reinterpret_cast<const short8*>(kh + (size_t)(j0 + it*16 + krow)*D + kch*8);
    #pragma unroll
    for(int it=0; it<4; ++it)
      vreg[it] = *reinterpret_cast<const short8*>(vTh + (size_t)(it*32 + vrow)*N + j0 + vch*8);
    u16x4 bb0[4], bb1[4];
    #pragma unroll
    for(int z=0; z<4; ++z){
      bb0[z] = *reinterpret_cast<const u16x4*>(brow0 + j0 + z*16 + g4*4);
      bb1[z] = *reinterpret_cast<const u16x4*>(brow1 + j0 + z*16 + g4*4);
    }

    __syncthreads();
    #pragma unroll
    for(int it=0; it<4; ++it){
      int row = it*16 + krow;
      *reinterpret_cast<short8*>(&Ks[row*128 + ((kch ^ (row&15))*8)]) = kreg[it];
    }
    #pragma unroll
    for(int it=0; it<4; ++it){
      int d = it*32 + vrow;
      int row = d & 63, ch = ((d>>6)<<3) | vch;
      *reinterpret_cast<short8*>(&Vs[row*128 + ((ch ^ (row&15))*8)]) = vreg[it];
    }
    __syncthreads();

    #pragma unroll
    for(int ks=0; ks<2; ++ks){
      short8 kf[8];
      const int rowA = ks*32 + l16, rowB = rowA + 16;
      #pragma unroll
      for(int c=0;c<4;c++){
        kf[c]   = *reinterpret_cast<const short8*>(&Ks[rowA*128 + (((c*4+g4) ^ l16)*8)]);
        kf[4+c] = *reinterpret_cast<const short8*>(&Ks[rowB*128 + (((c*4+g4) ^ l16)*8)]);
      }
      f32x4 sA0 = (f32x4){0.f,0.f,0.f,0.f}, sB0 = sA0, sA1 = sA0, sB1 = sA0;
      __builtin_amdgcn_s_setprio(1);
      #pragma unroll
      for(int c=0;c<4;c++){
        sA0 = __builtin_amdgcn_mfma_f32_16x16x32_bf16(kf[c],   qf0[c], sA0, 0, 0, 0);
        sB0 = __builtin_amdgcn_mfma_f32_16x16x32_bf16(kf[4+c], qf0[c], sB0, 0, 0, 0);
        sA1 = __builtin_amdgcn_mfma_f32_16x16x32_bf16(kf[c],   qf1[c], sA1, 0, 0, 0);
        sB1 = __builtin_amdgcn_mfma_f32_16x16x32_bf16(kf[4+c], qf1[c], sB1, 0, 0, 0);
      }
      __builtin_amdgcn_s_setprio(0);
      {
        u16x4 bA = bb0[2*ks], bB = bb0[2*ks+1];
        sA0[0] = fmaf(sA0[0], SCALE, bf2f(bA.x)); sA0[1] = fmaf(sA0[1], SCALE, bf2f(bA.y));
        sA0[2] = fmaf(sA0[2], SCALE, bf2f(bA.z)); sA0[3] = fmaf(sA0[3], SCALE, bf2f(bA.w));
        sB0[0] = fmaf(sB0[0], SCALE, bf2f(bB.x)); sB0[1] = fmaf(sB0[1], SCALE, bf2f(bB.y));
        sB0[2] = fmaf(sB0[2], SCALE, bf2f(bB.z)); sB0[3] = fmaf(sB0[3], SCALE, bf2f(bB.w));
      }
      {
        u16x4 bA = bb1[2*ks], bB = bb1[2*ks+1];
        sA1[0] = fmaf(sA1[0], SCALE, bf2f(bA.x)); sA1[1] = fmaf(sA1[1], SCALE, bf2f(bA.y));
        sA1[2] = fmaf(sA1[2], SCALE, bf2f(bA.z)); sA1[3] = fmaf(sA1[3], SCALE, bf2f(bA.w));
        sB1[0] = fmaf(sB1[0], SCALE, bf2f(bB.x)); sB1[1] = fmaf(sB1[1], SCALE, bf2f(bB.y));
        sB1[2] = fmaf(sB1[2], SCALE, bf2f(bB.z)); sB1[3] = fmaf(sB1[3], SCALE, bf2f(bB.w));
      }
      float p0 = fmaxf(fmaxf(fmaxf(sA0[0],sA0[1]), fmaxf(sA0[2],sA0[3])),
                       fmaxf(fmaxf(sB0[0],sB0[1]), fmaxf(sB0[2],sB0[3])));
      float p1 = fmaxf(fmaxf(fmaxf(sA1[0],sA1[1]), fmaxf(sA1[2],sA1[3])),
                       fmaxf(fmaxf(sB1[0],sB1[1]), fmaxf(sB1[2],sB1[3])));
      p0 = fmaxf(p0, __shfl_xor(p0, 16)); p0 = fmaxf(p0, __shfl_xor(p0, 32));
      p1 = fmaxf(p1, __shfl_xor(p1, 16)); p1 = fmaxf(p1, __shfl_xor(p1, 32));
      float dm = fmaxf(p0 - m0v, p1 - m1v);
      if(!__all(dm <= 8.0f)){
        float mn0 = fmaxf(m0v, p0), mn1 = fmaxf(m1v, p1);
        float cr0 = __expf(m0v - mn0), cr1 = __expf(m1v - mn1);
        ls0 *= cr0; ls1 *= cr1;
        #pragma unroll
        for(int rg=0;rg<4;++rg){
          float c0 = __shfl(cr0, (lane & 48) | (g4*4 + rg));
          float c1 = __shfl(cr1, (lane & 48) | (g4*4 + rg));
          #pragma unroll
          for(int dt=0;dt<8;dt++){ o0[dt][rg] *= c0; o1[dt][rg] *= c1; }
        }
        m0v = mn0; m1v = mn1;
      }
      f32x4 pA0, pB0, pA1, pB1;
      #pragma unroll
      for(int rg=0;rg<4;rg++){
        pA0[rg] = __expf(sA0[rg] - m0v); pB0[rg] = __expf(sB0[rg] - m0v);
        pA1[rg] = __expf(sA1[rg] - m1v); pB1[rg] = __expf(sB1[rg] - m1v);
      }
      float ps0 = (pA0[0]+pA0[1]) + (pA0[2]+pA0[3]) + ((pB0[0]+pB0[1]) + (pB0[2]+pB0[3]));
      float ps1 = (pA1[0]+pA1[1]) + (pA1[2]+pA1[3]) + ((pB1[0]+pB1[1]) + (pB1[2]+pB1[3]));
      ps0 += __shfl_xor(ps0, 16); ps0 += __shfl_xor(ps0, 32);
      ps1 += __shfl_xor(ps1, 16); ps1 += __shfl_xor(ps1, 32);
      ls0 += ps0; ls1 += ps1;
      u16x4 wa, wb;
      wa.x = f2bf(pA0[0]); wa.y = f2bf(pA0[1]); wa.z = f2bf(pA0[2]); wa.w = f2bf(pA0[3]);
      wb.x = f2bf(pB0[0]); wb.y = f2bf(pB0[1]); wb.z = f2bf(pB0[2]); wb.w = f2bf(pB0[3]);
      *reinterpret_cast<u16x4*>(&P[w][0][l16][g4*4])      = wa;
      *reinterpret_cast<u16x4*>(&P[w][0][l16][16 + g4*4]) = wb;
      wa.x = f2bf(pA1[0]); wa.y = f2bf(pA1[1]); wa.z = f2bf(pA1[2]); wa.w = f2bf(pA1[3]);
      wb.x = f2bf(pB1[0]); wb.y = f2bf(pB1[1]); wb.z = f2bf(pB1[2]); wb.w = f2bf(pB1[3]);
      *reinterpret_cast<u16x4*>(&P[w][1][l16][g4*4])      = wa;
      *reinterpret_cast<u16x4*>(&P[w][1][l16][16 + g4*4]) = wb;
      short8 pf0 = *reinterpret_cast<const short8*>(&P[w][0][l16][g4*8]);
      short8 pf1 = *reinterpret_cast<const short8*>(&P[w][1][l16][g4*8]);
      __builtin_amdgcn_s_setprio(1);
      #pragma unroll
      for(int dt=0;dt<8;dt++){
        int d = dt*16 + l16;
        int row = d & 63;
        int ch  = ((dt>>2)<<3) | (ks<<2) | g4;
        short8 vf = *reinterpret_cast<const short8*>(&Vs[row*128 + ((ch ^ l16)*8)]);
        o0[dt] = __builtin_amdgcn_mfma_f32_16x16x32_bf16(pf0, vf, o0[dt], 0, 0, 0);
        o1[dt] = __builtin_amdgcn_mfma_f32_16x16x32_bf16(pf1, vf, o1[dt], 0, 0, 0);
      }
      __builtin_amdgcn_s_setprio(0);
    }
  }

  float* ob0 = opart + ((size_t)((sp*H + head)*N) + r0)*D;
  float* ob1 = ob0 + (size_t)16*D;
  #pragma unroll
  for(int dt=0;dt<8;dt++){
    #pragma unroll
    for(int rg=0;rg<4;rg++){
      ob0[(size_t)(g4*4+rg)*D + dt*16 + l16] = o0[dt][rg];
      ob1[(size_t)(g4*4+rg)*D + dt*16 + l16] = o1[dt][rg];
    }
  }
  if(g4 == 0){
    mpart[(size_t)(sp*H + head)*N + r0 + l16]      = m0v;
    lpart[(size_t)(sp*H + head)*N + r0 + l16]      = ls0;
    mpart[(size_t)(sp*H + head)*N + r0 + 16 + l16] = m1v;
    lpart[(size_t)(sp*H + head)*N + r0 + 16 + l16] = ls1;
  }
}

// ---------------------------------------------------------------- launch
extern "C" void kernel_launch(void* const* d_in, const int* in_sizes, int n_in,
                              void* d_out, int out_size, void* d_ws, size_t ws_size,
                              hipStream_t stream){
  const float* x      = (const float*)d_in[0];
  const int*   ei     = (const int*)  d_in[1];
  const int*   spl    = (const int*)  d_in[2];
  const float* ef     = (const float*)d_in[3];
  const float* nodeW  = (const float*)d_in[4];
  const float* nodeb  = (const float*)d_in[5];
  const float* degemb = (const float*)d_in[6];
  const float* spe    = (const float*)d_in[7];
  const float* eW     = (const float*)d_in[8];
  const float* eb     = (const float*)d_in[9];
  const float* ln1g   = (const float*)d_in[10];
  const float* ln1b   = (const float*)d_in[11];
  const float* Wq     = (const float*)d_in[12];
  const float* bq     = (const float*)d_in[13];
  const float* Wk     = (const float*)d_in[14];
  const float* bk     = (const float*)d_in[15];
  const float* Wv     = (const float*)d_in[16];
  const float* bv     = (const float*)d_in[17];
  const float* Wo     = (const float*)d_in[18];
  const float* bo     = (const float*)d_in[19];
  const float* ln2g   = (const float*)d_in[20];
  const float* ln2b   = (const float*)d_in[21];
  const float* ffW    = (const float*)d_in[22];
  const float* ffb    = (const float*)d_in[23];
  const float* outW   = (const float*)d_in[24];
  const float* outb   = (const float*)d_in[25];

  constexpr size_t WT_ELEMS = 24*16384 + 2*16384 + 16384 + 2*65536;
  auto needed = [](int s)->size_t{
    size_t fl = 8192 + 3*(size_t)N*D;
    size_t bf = 3*(size_t)H*N*D + (size_t)N*N;
    size_t pf = (size_t)s*H*N*D + 2*(size_t)s*H*N;
    return fl*4 + bf*2 + pf*4 + WT_ELEMS*2;
  };
  int S = 2;
  if(needed(8) <= ws_size) S = 8;
  else if(needed(4) <= ws_size) S = 4;

  float* ws   = (float*)d_ws;
  int*   deg  = (int*)ws;
  float* mask = ws + 4096;
  float* h    = ws + 8192;
  float* xln  = h    + N*D;
  float* xout = xln  + N*D;
  u16*   qb   = (u16*)(xout + N*D);
  u16*   kb   = qb + (size_t)H*N*D;
  u16*   vTb  = kb + (size_t)H*N*D;
  u16*   biasm= vTb + (size_t)H*N*D;
  float* opart= (float*)(biasm + (size_t)N*N);
  float* mpart= opart + (size_t)S*H*N*D;
  float* lpart= mpart + (size_t)S*H*N;
  u16*   wt_qkv = (u16*)(lpart + (size_t)S*H*N);
  u16*   wt_ff  = wt_qkv + 24*16384;
  u16*   wt_out = wt_ff  + 2*16384;
  u16*   wt_wo  = wt_out + 16384;

  k_wt_all<<<dim3(16, 27), 256, 0, stream>>>(Wq, Wk, Wv, ffW, outW, wt_qkv, wt_ff, wt_out);
  k_wt_wo<<<dim3(64, 2), 256, 0, stream>>>(Wo, wt_wo);
  k_zero_deg<<<(N+255)/256, 256, 0, stream>>>(deg);
  k_deg<<<(E+255)/256, 256, 0, stream>>>(ei, deg);
  k_h0<<<N, 64, 0, stream>>>(x, nodeW, nodeb, degemb, deg, ln1g, ln1b, mask, h, xln);
  k_bias<<<(N*N)/256, 256, 0, stream>>>(spl, ef, spe, eW, eb, mask, biasm);

  for(int l = 0; l < 2; ++l){
    k_mqkv<<<dim3(N/64, 12), 256, 0, stream>>>(xln, wt_qkv, bq, bk, bv, qb, kb, vTb, l);
    k_attn<<<dim3(N/128, H, S), 256, 0, stream>>>(qb, kb, vTb, biasm, opart, mpart, lpart, N/S);
    if(S == 8)
      k_mwo<8><<<N/64, 256, 0, stream>>>(opart, mpart, lpart, mask, wt_wo + (size_t)l*65536,
                                         bo + l*D, h, xout, xln, ln2g + l*D, ln2b + l*D);
    else if(S == 4)
      k_mwo<4><<<N/64, 256, 0, stream>>>(opart, mpart, lpart, mask, wt_wo + (size_t)l*65536,
                                         bo + l*D, h, xout, xln, ln2g + l*D, ln2b + l*D);
    else
      k_mwo<2><<<N/64, 256, 0, stream>>>(opart, mpart, lpart, mask, wt_wo + (size_t)l*65536,
                                         bo + l*D, h, xout, xln, ln2g + l*D, ln2b + l*D);
    k_mff<<<N/64, 256, 0, stream>>>(xln, wt_ff + (size_t)l*16384, ffb + l*D, xout, h, xln,
                                    ln1g + (l==0 ? D : 0), ln1b + (l==0 ? D : 0), l==0 ? 1 : 0);
  }
  k_mout<<<N/64, 256, 0, stream>>>(h, wt_out, outb, (float*)d_out);
}

// Round 10
// 246.637 us; speedup vs baseline: 1.1061x; 1.1061x over previous
//
#include <hip/hip_runtime.h>
#include <math.h>

static constexpr int N   = 3072;
static constexpr int DIN = 64;
static constexpr int D   = 128;
static constexpr int H   = 4;
static constexpr int E   = 49152;
#define NEGV  (-4294967295.0f)
#define SCALE (0.08838834764831845f)   // 1/sqrt(128)

typedef unsigned short u16;
typedef __attribute__((ext_vector_type(8))) short short8;
typedef __attribute__((ext_vector_type(4))) float f32x4;
typedef __attribute__((ext_vector_type(4))) unsigned short u16x4;

__device__ __forceinline__ u16 f2bf(float f){           // RNE float->bf16
  unsigned int u = __float_as_uint(f);
  u += 0x7fff + ((u >> 16) & 1);
  return (u16)(u >> 16);
}
__device__ __forceinline__ float bf2f(u16 u){
  return __uint_as_float(((unsigned int)u) << 16);
}

// ---------------------------------------------------------------- deg
__global__ void k_zero_deg(int* __restrict__ deg){
  int i = blockIdx.x*blockDim.x + threadIdx.x;
  if(i < N) deg[i] = 0;
}

__global__ void k_deg(const int* __restrict__ ei, int* __restrict__ deg){
  int e = blockIdx.x*blockDim.x + threadIdx.x;
  if(e < E) atomicAdd(&deg[ei[E + e]], 1);
}

// ---------------------------------------------------------------- h0 + fused LN1(layer0)
__global__ void k_h0(const float* __restrict__ x, const float* __restrict__ nodeW,
                     const float* __restrict__ nodeb, const float* __restrict__ degemb,
                     const int* __restrict__ deg, const float* __restrict__ g1,
                     const float* __restrict__ b1, float* __restrict__ mask,
                     float* __restrict__ h, float* __restrict__ xln){
  const int i = blockIdx.x, t = threadIdx.x;
  float xv = x[i*DIN + t];
  float s = xv;
  #pragma unroll
  for(int o=32;o;o>>=1) s += __shfl_xor(s, o);
  if(t == 0) mask[i] = (s != 0.0f) ? 1.0f : 0.0f;
  __shared__ float xr[DIN];
  xr[t] = xv;
  __syncthreads();
  int dg = deg[i]; dg = dg > N-1 ? N-1 : dg;
  float a0 = nodeb[t]      + degemb[dg*D + t];
  float a1 = nodeb[t + 64] + degemb[dg*D + t + 64];
  #pragma unroll
  for(int u=0; u<DIN; ++u){
    float xu = xr[u];
    a0 = fmaf(xu, nodeW[u*D + t],      a0);
    a1 = fmaf(xu, nodeW[u*D + t + 64], a1);
  }
  h[i*D + t]      = a0;
  h[i*D + t + 64] = a1;
  float s2 = a0 + a1, sq = a0*a0 + a1*a1;
  #pragma unroll
  for(int o=32;o;o>>=1){ s2 += __shfl_xor(s2, o); sq += __shfl_xor(sq, o); }
  float mean = s2*(1.0f/128.0f);
  float var  = sq*(1.0f/128.0f) - mean*mean;
  float inv  = rsqrtf(var + 1e-5f);
  xln[i*D + t]      = (a0 - mean)*inv*g1[t]      + b1[t];
  xln[i*D + t + 64] = (a1 - mean)*inv*g1[t + 64] + b1[t + 64];
}

// ---------------------------------------------------------------- bias (masked, bf16)
__global__ void k_bias(const int* __restrict__ spl, const float* __restrict__ ef,
                       const float* __restrict__ spe, const float* __restrict__ eW,
                       const float* __restrict__ eb, const float* __restrict__ mask,
                       u16* __restrict__ biasm){
  int idx = blockIdx.x*blockDim.x + threadIdx.x;   // < N*N
  int i = idx / N, j = idx % N;
  float wm0 = (eW[0] + eW[1] + eW[2] + eW[3])  * 0.25f;
  float wm1 = (eW[4] + eW[5] + eW[6] + eW[7])  * 0.25f;
  float wm2 = (eW[8] + eW[9] + eW[10]+ eW[11]) * 0.25f;
  float wm3 = (eW[12]+ eW[13]+ eW[14]+ eW[15]) * 0.25f;
  float bm  = (eb[0] + eb[1] + eb[2] + eb[3])  * 0.25f;
  float4 e4 = reinterpret_cast<const float4*>(ef)[idx];
  float em = fmaf(e4.x, wm0, fmaf(e4.y, wm1, fmaf(e4.z, wm2, fmaf(e4.w, wm3, bm))));
  float b = spe[spl[idx]] + em;
  float mk = mask[i]*mask[j];
  biasm[idx] = f2bf((mk != 0.0f) ? b : NEGV);
}

// ---------------------------------------------------------------- weight prep: fp32 [K][128] -> bf16 Bt [128][K]
__global__ __launch_bounds__(256) void k_wt_all(const float* __restrict__ Wq, const float* __restrict__ Wk,
    const float* __restrict__ Wv, const float* __restrict__ ffW, const float* __restrict__ outW,
    u16* __restrict__ wt_qkv, u16* __restrict__ wt_ff, u16* __restrict__ wt_out){
  __shared__ float t[32][33];
  const int z = blockIdx.y;
  const float* src; u16* dst;
  if(z < 24){
    int l = z/12, r = z%12;
    const float* W = (r>>2)==0 ? Wq : (r>>2)==1 ? Wk : Wv;
    src = W + (size_t)(l*4 + (r&3))*16384;
    dst = wt_qkv + (size_t)z*16384;
  } else if(z < 26){
    src = ffW + (size_t)(z-24)*16384; dst = wt_ff + (size_t)(z-24)*16384;
  } else { src = outW; dst = wt_out; }
  const int ki = blockIdx.x & 3, ni = blockIdx.x >> 2;
  const int tid = threadIdx.x;
  #pragma unroll
  for(int i=0;i<4;i++){
    int idx = tid + i*256, r = idx>>5, c = idx&31;
    t[r][c] = src[(size_t)(ki*32+r)*128 + ni*32 + c];
  }
  __syncthreads();
  #pragma unroll
  for(int i=0;i<4;i++){
    int idx = tid + i*256, r = idx>>5, c = idx&31;
    dst[(size_t)(ni*32+r)*128 + ki*32 + c] = f2bf(t[c][r]);
  }
}

__global__ __launch_bounds__(256) void k_wt_wo(const float* __restrict__ Wo, u16* __restrict__ wt_wo){
  __shared__ float t[32][33];
  const int l = blockIdx.y;
  const float* src = Wo + (size_t)l*65536;
  u16* dst = wt_wo + (size_t)l*65536;
  const int ki = blockIdx.x & 15, ni = blockIdx.x >> 4;
  const int tid = threadIdx.x;
  #pragma unroll
  for(int i=0;i<4;i++){
    int idx = tid + i*256, r = idx>>5, c = idx&31;
    t[r][c] = src[(size_t)(ki*32+r)*128 + ni*32 + c];
  }
  __syncthreads();
  #pragma unroll
  for(int i=0;i<4;i++){
    int idx = tid + i*256, r = idx>>5, c = idx&31;
    dst[(size_t)(ni*32+r)*512 + ki*32 + c] = f2bf(t[c][r]);
  }
}

// ---------------------------------------------------------------- bf16 MFMA GEMM (K=128), C = A@Bt^T + bias
// MODE: 0 = fp32 row-major, 1 = bf16 row-major, 2 = bf16 transposed (vT[d][n], coalesced via LDS)
template<int MODE>
__device__ __forceinline__ void mgemm_body(const float* __restrict__ A, const u16* __restrict__ Bt,
                                           const float* __restrict__ bias, void* __restrict__ Cv){
  __shared__ u16 As[64*128];
  __shared__ u16 Bs[128*128];
  const int tid = threadIdx.x, w = tid>>6, lane = tid&63;
  const int g4 = lane>>4, l16 = lane&15;
  const int m0 = blockIdx.x*64;
  const int srow = tid>>4, sch = tid&15;
  f32x4 acc[8];
  #pragma unroll
  for(int nt=0;nt<8;++nt) acc[nt] = (f32x4){0.f,0.f,0.f,0.f};
  #pragma unroll
  for(int it=0;it<4;++it){
    int row = it*16 + srow;
    const float4* ap = reinterpret_cast<const float4*>(A + (size_t)(m0+row)*128 + sch*8);
    float4 x0 = ap[0], x1 = ap[1];
    u16x4 p0, p1;
    p0.x=f2bf(x0.x); p0.y=f2bf(x0.y); p0.z=f2bf(x0.z); p0.w=f2bf(x0.w);
    p1.x=f2bf(x1.x); p1.y=f2bf(x1.y); p1.z=f2bf(x1.z); p1.w=f2bf(x1.w);
    u16* dst = &As[row*128 + ((sch ^ (row&15))*8)];
    *reinterpret_cast<u16x4*>(dst)     = p0;
    *reinterpret_cast<u16x4*>(dst + 4) = p1;
  }
  #pragma unroll
  for(int it=0;it<8;++it){
    int row = it*16 + srow;
    short8 b = *reinterpret_cast<const short8*>(Bt + (size_t)row*128 + sch*8);
    *reinterpret_cast<short8*>(&Bs[row*128 + ((sch ^ (row&15))*8)]) = b;
  }
  __syncthreads();
  __builtin_amdgcn_s_setprio(1);
  #pragma unroll
  for(int c=0;c<4;++c){
    short8 af = *reinterpret_cast<const short8*>(&As[(w*16+l16)*128 + (((c*4+g4) ^ l16)*8)]);
    #pragma unroll
    for(int nt=0;nt<8;++nt){
      short8 bf = *reinterpret_cast<const short8*>(&Bs[(nt*16+l16)*128 + (((c*4+g4) ^ l16)*8)]);
      acc[nt] = __builtin_amdgcn_mfma_f32_16x16x32_bf16(af, bf, acc[nt], 0, 0, 0);
    }
  }
  __builtin_amdgcn_s_setprio(0);
  const int mrow = m0 + w*16 + g4*4;
  if(MODE == 2){
    __syncthreads();
    u16* T = Bs;                                   // [col][64 rows], stride 68
    #pragma unroll
    for(int nt=0;nt<8;++nt){
      const int col = nt*16 + l16;
      float bi = bias[col];
      u16x4 t;
      t.x = f2bf(acc[nt][0] + bi); t.y = f2bf(acc[nt][1] + bi);
      t.z = f2bf(acc[nt][2] + bi); t.w = f2bf(acc[nt][3] + bi);
      *reinterpret_cast<u16x4*>(&T[col*68 + (w*16 + g4*4)]) = t;
    }
    __syncthreads();
    #pragma unroll
    for(int i=0;i<4;++i){
      int slot = tid + i*256;
      int col = slot >> 3, q = slot & 7;
      short8 v = *reinterpret_cast<const short8*>(&T[col*68 + q*8]);
      *reinterpret_cast<short8*>((u16*)Cv + (size_t)col*N + m0 + q*8) = v;
    }
  } else {
    #pragma unroll
    for(int nt=0;nt<8;++nt){
      const int col = nt*16 + l16;
      float bi = bias[col];
      #pragma unroll
      for(int rg=0;rg<4;++rg){
        float v = acc[nt][rg] + bi;
        if(MODE == 1) ((u16*)Cv)[(size_t)(mrow+rg)*128 + col] = f2bf(v);
        else          ((float*)Cv)[(size_t)(mrow+rg)*128 + col] = v;
      }
    }
  }
}

// grid (N/64, 12): z = which*4 + head. V written directly transposed (vT[h][d][n]).
__global__ __launch_bounds__(256) void k_mqkv(const float* __restrict__ xln, const u16* __restrict__ wt_qkv,
    const float* __restrict__ bq, const float* __restrict__ bk, const float* __restrict__ bv,
    u16* __restrict__ q, u16* __restrict__ k, u16* __restrict__ vT, int l){
  const int z = blockIdx.y, which = z>>2, head = z&3;
  const u16* Bt = wt_qkv + (size_t)(l*12 + z)*16384;
  if(which == 0)      mgemm_body<1>(xln, Bt, bq + (l*H+head)*D, q  + (size_t)head*N*D);
  else if(which == 1) mgemm_body<1>(xln, Bt, bk + (l*H+head)*D, k  + (size_t)head*N*D);
  else                mgemm_body<2>(xln, Bt, bv + (l*H+head)*D, vT + (size_t)head*N*D);
}

__global__ __launch_bounds__(256) void k_mout(const float* __restrict__ h, const u16* __restrict__ wt_out,
    const float* __restrict__ outb, float* __restrict__ out){
  mgemm_body<0>(h, wt_out, outb, out);
}

// ---------------------------------------------------------------- Wo GEMM, fused split-K combine (bf16 partials) + LN2
template<int S>
__global__ __launch_bounds__(256) void k_mwo(const u16* __restrict__ opart, const float* __restrict__ mpart,
    const float* __restrict__ lpart, const float* __restrict__ mask, const u16* __restrict__ wt,
    const float* __restrict__ bo, const float* __restrict__ hres,
    float* __restrict__ xout, float* __restrict__ xln,
    const float* __restrict__ g2, const float* __restrict__ b2){
  __shared__ u16 As[64*128];
  __shared__ u16 Bs[128*128];
  const int tid = threadIdx.x, w = tid>>6, lane = tid&63;
  const int g4 = lane>>4, l16 = lane&15;
  const int m0 = blockIdx.x*64;
  const int srow = tid>>4, sch = tid&15;
  f32x4 acc[8];
  #pragma unroll
  for(int nt=0;nt<8;++nt) acc[nt] = (f32x4){0.f,0.f,0.f,0.f};
  for(int k0 = 0; k0 < 512; k0 += 128){
    const int hh = k0 >> 7;
    __syncthreads();
    #pragma unroll
    for(int it=0;it<4;++it){
      int row = it*16 + srow;
      int grow = m0 + row;
      float w_[S]; float M = -INFINITY; float mv[S], lv[S];
      #pragma unroll
      for(int s=0;s<S;++s){
        mv[s] = mpart[(size_t)(s*H + hh)*N + grow];
        lv[s] = lpart[(size_t)(s*H + hh)*N + grow];
        M = fmaxf(M, mv[s]);
      }
      float denom = 0.f;
      #pragma unroll
      for(int s=0;s<S;++s){ w_[s] = __expf(mv[s] - M); denom = fmaf(lv[s], w_[s], denom); }
      float scale = mask[grow] / denom;
      const int d = sch*8;
      float v[8] = {0,0,0,0,0,0,0,0};
      #pragma unroll
      for(int s=0;s<S;++s){
        short8 ov = *reinterpret_cast<const short8*>(
            opart + ((size_t)(s*H + hh)*N + grow)*D + d);
        #pragma unroll
        for(int j=0;j<8;++j) v[j] = fmaf(bf2f((u16)ov[j]), w_[s], v[j]);
      }
      u16x4 p0, p1;
      p0.x=f2bf(v[0]*scale); p0.y=f2bf(v[1]*scale); p0.z=f2bf(v[2]*scale); p0.w=f2bf(v[3]*scale);
      p1.x=f2bf(v[4]*scale); p1.y=f2bf(v[5]*scale); p1.z=f2bf(v[6]*scale); p1.w=f2bf(v[7]*scale);
      u16* dst = &As[row*128 + ((sch ^ (row&15))*8)];
      *reinterpret_cast<u16x4*>(dst)     = p0;
      *reinterpret_cast<u16x4*>(dst + 4) = p1;
    }
    #pragma unroll
    for(int it=0;it<8;++it){
      int row = it*16 + srow;
      short8 b = *reinterpret_cast<const short8*>(wt + (size_t)row*512 + k0 + sch*8);
      *reinterpret_cast<short8*>(&Bs[row*128 + ((sch ^ (row&15))*8)]) = b;
    }
    __syncthreads();
    __builtin_amdgcn_s_setprio(1);
    #pragma unroll
    for(int c=0;c<4;++c){
      short8 af = *reinterpret_cast<const short8*>(&As[(w*16+l16)*128 + (((c*4+g4) ^ l16)*8)]);
      #pragma unroll
      for(int nt=0;nt<8;++nt){
        short8 bf = *reinterpret_cast<const short8*>(&Bs[(nt*16+l16)*128 + (((c*4+g4) ^ l16)*8)]);
        acc[nt] = __builtin_amdgcn_mfma_f32_16x16x32_bf16(af, bf, acc[nt], 0, 0, 0);
      }
    }
    __builtin_amdgcn_s_setprio(0);
  }
  const int mrow = m0 + w*16 + g4*4;
  float s_[4] = {0,0,0,0}, q_[4] = {0,0,0,0};
  #pragma unroll
  for(int nt=0;nt<8;++nt){
    const int col = nt*16 + l16;
    float bi = bo[col];
    #pragma unroll
    for(int rg=0;rg<4;++rg){
      float v = acc[nt][rg] + bi + hres[(size_t)(mrow+rg)*128 + col];
      acc[nt][rg] = v;
      s_[rg] += v; q_[rg] = fmaf(v, v, q_[rg]);
    }
  }
  #pragma unroll
  for(int o=1;o<16;o<<=1){
    #pragma unroll
    for(int rg=0;rg<4;++rg){ s_[rg] += __shfl_xor(s_[rg], o); q_[rg] += __shfl_xor(q_[rg], o); }
  }
  float mean[4], inv[4];
  #pragma unroll
  for(int rg=0;rg<4;++rg){
    mean[rg] = s_[rg]*(1.0f/128.0f);
    float var = q_[rg]*(1.0f/128.0f) - mean[rg]*mean[rg];
    inv[rg] = rsqrtf(var + 1e-5f);
  }
  #pragma unroll
  for(int nt=0;nt<8;++nt){
    const int col = nt*16 + l16;
    float gg = g2[col], bb = b2[col];
    #pragma unroll
    for(int rg=0;rg<4;++rg){
      float v = acc[nt][rg];
      xout[(size_t)(mrow+rg)*128 + col] = v;
      xln [(size_t)(mrow+rg)*128 + col] = (v - mean[rg])*inv[rg]*gg + bb;
    }
  }
}

// ---------------------------------------------------------------- FF GEMM + residual, fused LN1(l+1) epilogue
__global__ __launch_bounds__(256) void k_mff(const float* __restrict__ xlnin, const u16* __restrict__ wt,
    const float* __restrict__ ffb, const float* __restrict__ res, float* __restrict__ hout,
    float* __restrict__ xlnout, const float* __restrict__ g1n, const float* __restrict__ b1n,
    int write_ln){
  __shared__ u16 As[64*128];
  __shared__ u16 Bs[128*128];
  const int tid = threadIdx.x, w = tid>>6, lane = tid&63;
  const int g4 = lane>>4, l16 = lane&15;
  const int m0 = blockIdx.x*64;
  const int srow = tid>>4, sch = tid&15;
  f32x4 acc[8];
  #pragma unroll
  for(int nt=0;nt<8;++nt) acc[nt] = (f32x4){0.f,0.f,0.f,0.f};
  #pragma unroll
  for(int it=0;it<4;++it){
    int row = it*16 + srow;
    const float4* ap = reinterpret_cast<const float4*>(xlnin + (size_t)(m0+row)*128 + sch*8);
    float4 x0 = ap[0], x1 = ap[1];
    u16x4 p0, p1;
    p0.x=f2bf(x0.x); p0.y=f2bf(x0.y); p0.z=f2bf(x0.z); p0.w=f2bf(x0.w);
    p1.x=f2bf(x1.x); p1.y=f2bf(x1.y); p1.z=f2bf(x1.z); p1.w=f2bf(x1.w);
    u16* dst = &As[row*128 + ((sch ^ (row&15))*8)];
    *reinterpret_cast<u16x4*>(dst)     = p0;
    *reinterpret_cast<u16x4*>(dst + 4) = p1;
  }
  #pragma unroll
  for(int it=0;it<8;++it){
    int row = it*16 + srow;
    short8 b = *reinterpret_cast<const short8*>(wt + (size_t)row*128 + sch*8);
    *reinterpret_cast<short8*>(&Bs[row*128 + ((sch ^ (row&15))*8)]) = b;
  }
  __syncthreads();
  __builtin_amdgcn_s_setprio(1);
  #pragma unroll
  for(int c=0;c<4;++c){
    short8 af = *reinterpret_cast<const short8*>(&As[(w*16+l16)*128 + (((c*4+g4) ^ l16)*8)]);
    #pragma unroll
    for(int nt=0;nt<8;++nt){
      short8 bf = *reinterpret_cast<const short8*>(&Bs[(nt*16+l16)*128 + (((c*4+g4) ^ l16)*8)]);
      acc[nt] = __builtin_amdgcn_mfma_f32_16x16x32_bf16(af, bf, acc[nt], 0, 0, 0);
    }
  }
  __builtin_amdgcn_s_setprio(0);
  const int mrow = m0 + w*16 + g4*4;
  float s_[4] = {0,0,0,0}, q_[4] = {0,0,0,0};
  #pragma unroll
  for(int nt=0;nt<8;++nt){
    const int col = nt*16 + l16;
    float bi = ffb[col];
    #pragma unroll
    for(int rg=0;rg<4;++rg){
      float v = acc[nt][rg] + bi + res[(size_t)(mrow+rg)*128 + col];
      acc[nt][rg] = v;
      s_[rg] += v; q_[rg] = fmaf(v, v, q_[rg]);
    }
  }
  #pragma unroll
  for(int nt=0;nt<8;++nt){
    const int col = nt*16 + l16;
    #pragma unroll
    for(int rg=0;rg<4;++rg)
      hout[(size_t)(mrow+rg)*128 + col] = acc[nt][rg];
  }
  if(write_ln){
    #pragma unroll
    for(int o=1;o<16;o<<=1){
      #pragma unroll
      for(int rg=0;rg<4;++rg){ s_[rg] += __shfl_xor(s_[rg], o); q_[rg] += __shfl_xor(q_[rg], o); }
    }
    #pragma unroll
    for(int rg=0;rg<4;++rg){
      float mean = s_[rg]*(1.0f/128.0f);
      float var  = q_[rg]*(1.0f/128.0f) - mean*mean;
      float inv  = rsqrtf(var + 1e-5f);
      s_[rg] = mean; q_[rg] = inv;
    }
    #pragma unroll
    for(int nt=0;nt<8;++nt){
      const int col = nt*16 + l16;
      float gg = g1n[col], bb = b1n[col];
      #pragma unroll
      for(int rg=0;rg<4;++rg)
        xlnout[(size_t)(mrow+rg)*128 + col] = (acc[nt][rg] - s_[rg])*q_[rg]*gg + bb;
    }
  }
}

// ---------------------------------------------------------------- MFMA flash attention, QBLK=32/wave, VGPR-capped
// Block = 256 thr (4 waves, 3 waves/EU forced), 128 q-rows; grid (N/128, H, SPLIT=8).
__global__ __launch_bounds__(256, 3) void k_attn(const u16* __restrict__ q, const u16* __restrict__ k,
                     const u16* __restrict__ vT, const u16* __restrict__ biasm,
                     u16* __restrict__ opart, float* __restrict__ mpart, float* __restrict__ lpart,
                     int kvlen){
  const int tid  = threadIdx.x;
  const int w    = tid >> 6;
  const int lane = tid & 63;
  const int g4 = lane >> 4, l16 = lane & 15;
  const int head = blockIdx.y, sp = blockIdx.z;
  const int r0 = blockIdx.x*128 + w*32;
  __shared__ u16 Ks[64*128];          // [key][128 dims], swizzled
  __shared__ u16 Vs[64*128];          // [d&63][seg | 64 keys], swizzled
  __shared__ u16 P[4][2][16][40];     // per-wave, per-group

  const u16* qbase = q + ((size_t)head*N + r0)*D;
  short8 qf0[4], qf1[4];
  #pragma unroll
  for(int c=0;c<4;c++){
    qf0[c] = *reinterpret_cast<const short8*>(qbase + l16*D + c*32 + g4*8);
    qf1[c] = *reinterpret_cast<const short8*>(qbase + (16+l16)*D + c*32 + g4*8);
  }

  f32x4 o0[8], o1[8];
  #pragma unroll
  for(int dt=0;dt<8;dt++){ o0[dt] = (f32x4){0.f,0.f,0.f,0.f}; o1[dt] = o0[dt]; }
  float m0v = -INFINITY, ls0 = 0.0f;
  float m1v = -INFINITY, ls1 = 0.0f;

  const u16* kh   = k  + (size_t)head*N*D;
  const u16* vTh  = vT + (size_t)head*D*N;
  const u16* brow0 = biasm + (size_t)(r0 + l16)*N;
  const u16* brow1 = biasm + (size_t)(r0 + 16 + l16)*N;
  const int kv0 = sp*kvlen;

  const int krow = tid >> 4, kch = tid & 15;
  const int vrow = tid >> 3, vch = tid & 7;

  for(int j0 = kv0; j0 < kv0 + kvlen; j0 += 64){
    short8 kreg[4], vreg[4];
    #pragma unroll
    for(int it=0; it<4; ++it)
      kreg[it] = *reinterpret_cast<const short8*>(kh + (size_t)(j0 + it*16 + krow)*D + kch*8);
    #pragma unroll
    for(int it=0; it<4; ++it)
      vreg[it] = *reinterpret_cast<const short8*>(vTh + (size_t)(it*32 + vrow)*N + j0 + vch*8);

    __syncthreads();
    #pragma unroll
    for(int it=0; it<4; ++it){
      int row = it*16 + krow;
      *reinterpret_cast<short8*>(&Ks[row*128 + ((kch ^ (row&15))*8)]) = kreg[it];
    }
    #pragma unroll
    for(int it=0; it<4; ++it){
      int d = it*32 + vrow;
      int row = d & 63, ch = ((d>>6)<<3) | vch;
      *reinterpret_cast<short8*>(&Vs[row*128 + ((ch ^ (row&15))*8)]) = vreg[it];
    }
    __syncthreads();

    #pragma unroll
    for(int ks=0; ks<2; ++ks){
      // bias loads (L3-resident) issued here, consumed after MFMA
      u16x4 bA0 = *reinterpret_cast<const u16x4*>(brow0 + j0 + ks*32 + g4*4);
      u16x4 bB0 = *reinterpret_cast<const u16x4*>(brow0 + j0 + ks*32 + 16 + g4*4);
      u16x4 bA1 = *reinterpret_cast<const u16x4*>(brow1 + j0 + ks*32 + g4*4);
      u16x4 bB1 = *reinterpret_cast<const u16x4*>(brow1 + j0 + ks*32 + 16 + g4*4);
      short8 kf[8];
      const int rowA = ks*32 + l16, rowB = rowA + 16;
      #pragma unroll
      for(int c=0;c<4;c++){
        kf[c]   = *reinterpret_cast<const short8*>(&Ks[rowA*128 + (((c*4+g4) ^ l16)*8)]);
        kf[4+c] = *reinterpret_cast<const short8*>(&Ks[rowB*128 + (((c*4+g4) ^ l16)*8)]);
      }
      f32x4 sA0 = (f32x4){0.f,0.f,0.f,0.f}, sB0 = sA0, sA1 = sA0, sB1 = sA0;
      __builtin_amdgcn_s_setprio(1);
      #pragma unroll
      for(int c=0;c<4;c++){
        sA0 = __builtin_amdgcn_mfma_f32_16x16x32_bf16(kf[c],   qf0[c], sA0, 0, 0, 0);
        sB0 = __builtin_amdgcn_mfma_f32_16x16x32_bf16(kf[4+c], qf0[c], sB0, 0, 0, 0);
        sA1 = __builtin_amdgcn_mfma_f32_16x16x32_bf16(kf[c],   qf1[c], sA1, 0, 0, 0);
        sB1 = __builtin_amdgcn_mfma_f32_16x16x32_bf16(kf[4+c], qf1[c], sB1, 0, 0, 0);
      }
      __builtin_amdgcn_s_setprio(0);
      sA0[0] = fmaf(sA0[0], SCALE, bf2f(bA0.x)); sA0[1] = fmaf(sA0[1], SCALE, bf2f(bA0.y));
      sA0[2] = fmaf(sA0[2], SCALE, bf2f(bA0.z)); sA0[3] = fmaf(sA0[3], SCALE, bf2f(bA0.w));
      sB0[0] = fmaf(sB0[0], SCALE, bf2f(bB0.x)); sB0[1] = fmaf(sB0[1], SCALE, bf2f(bB0.y));
      sB0[2] = fmaf(sB0[2], SCALE, bf2f(bB0.z)); sB0[3] = fmaf(sB0[3], SCALE, bf2f(bB0.w));
      sA1[0] = fmaf(sA1[0], SCALE, bf2f(bA1.x)); sA1[1] = fmaf(sA1[1], SCALE, bf2f(bA1.y));
      sA1[2] = fmaf(sA1[2], SCALE, bf2f(bA1.z)); sA1[3] = fmaf(sA1[3], SCALE, bf2f(bA1.w));
      sB1[0] = fmaf(sB1[0], SCALE, bf2f(bB1.x)); sB1[1] = fmaf(sB1[1], SCALE, bf2f(bB1.y));
      sB1[2] = fmaf(sB1[2], SCALE, bf2f(bB1.z)); sB1[3] = fmaf(sB1[3], SCALE, bf2f(bB1.w));
      float p0 = fmaxf(fmaxf(fmaxf(sA0[0],sA0[1]), fmaxf(sA0[2],sA0[3])),
                       fmaxf(fmaxf(sB0[0],sB0[1]), fmaxf(sB0[2],sB0[3])));
      float p1 = fmaxf(fmaxf(fmaxf(sA1[0],sA1[1]), fmaxf(sA1[2],sA1[3])),
                       fmaxf(fmaxf(sB1[0],sB1[1]), fmaxf(sB1[2],sB1[3])));
      p0 = fmaxf(p0, __shfl_xor(p0, 16)); p0 = fmaxf(p0, __shfl_xor(p0, 32));
      p1 = fmaxf(p1, __shfl_xor(p1, 16)); p1 = fmaxf(p1, __shfl_xor(p1, 32));
      float dm = fmaxf(p0 - m0v, p1 - m1v);
      if(!__all(dm <= 8.0f)){
        float mn0 = fmaxf(m0v, p0), mn1 = fmaxf(m1v, p1);
        float cr0 = __expf(m0v - mn0), cr1 = __expf(m1v - mn1);
        ls0 *= cr0; ls1 *= cr1;
        #pragma unroll
        for(int rg=0;rg<4;++rg){
          float c0 = __shfl(cr0, (lane & 48) | (g4*4 + rg));
          float c1 = __shfl(cr1, (lane & 48) | (g4*4 + rg));
          #pragma unroll
          for(int dt=0;dt<8;dt++){ o0[dt][rg] *= c0; o1[dt][rg] *= c1; }
        }
        m0v = mn0; m1v = mn1;
      }
      f32x4 pA0, pB0, pA1, pB1;
      #pragma unroll
      for(int rg=0;rg<4;rg++){
        pA0[rg] = __expf(sA0[rg] - m0v); pB0[rg] = __expf(sB0[rg] - m0v);
        pA1[rg] = __expf(sA1[rg] - m1v); pB1[rg] = __expf(sB1[rg] - m1v);
      }
      float ps0 = (pA0[0]+pA0[1]) + (pA0[2]+pA0[3]) + ((pB0[0]+pB0[1]) + (pB0[2]+pB0[3]));
      float ps1 = (pA1[0]+pA1[1]) + (pA1[2]+pA1[3]) + ((pB1[0]+pB1[1]) + (pB1[2]+pB1[3]));
      ps0 += __shfl_xor(ps0, 16); ps0 += __shfl_xor(ps0, 32);
      ps1 += __shfl_xor(ps1, 16); ps1 += __shfl_xor(ps1, 32);
      ls0 += ps0; ls1 += ps1;
      u16x4 wa, wb;
      wa.x = f2bf(pA0[0]); wa.y = f2bf(pA0[1]); wa.z = f2bf(pA0[2]); wa.w = f2bf(pA0[3]);
      wb.x = f2bf(pB0[0]); wb.y = f2bf(pB0[1]); wb.z = f2bf(pB0[2]); wb.w = f2bf(pB0[3]);
      *reinterpret_cast<u16x4*>(&P[w][0][l16][g4*4])      = wa;
      *reinterpret_cast<u16x4*>(&P[w][0][l16][16 + g4*4]) = wb;
      wa.x = f2bf(pA1[0]); wa.y = f2bf(pA1[1]); wa.z = f2bf(pA1[2]); wa.w = f2bf(pA1[3]);
      wb.x = f2bf(pB1[0]); wb.y = f2bf(pB1[1]); wb.z = f2bf(pB1[2]); wb.w = f2bf(pB1[3]);
      *reinterpret_cast<u16x4*>(&P[w][1][l16][g4*4])      = wa;
      *reinterpret_cast<u16x4*>(&P[w][1][l16][16 + g4*4]) = wb;
      short8 pf0 = *reinterpret_cast<const short8*>(&P[w][0][l16][g4*8]);
      short8 pf1 = *reinterpret_cast<const short8*>(&P[w][1][l16][g4*8]);
      __builtin_amdgcn_s_setprio(1);
      #pragma unroll
      for(int dt=0;dt<8;dt++){
        int d = dt*16 + l16;
        int row = d & 63;
        int ch  = ((dt>>2)<<3) | (ks<<2) | g4;
        short8 vf = *reinterpret_cast<const short8*>(&Vs[row*128 + ((ch ^ l16)*8)]);
        o0[dt] = __builtin_amdgcn_mfma_f32_16x16x32_bf16(pf0, vf, o0[dt], 0, 0, 0);
        o1[dt] = __builtin_amdgcn_mfma_f32_16x16x32_bf16(pf1, vf, o1[dt], 0, 0, 0);
      }
      __builtin_amdgcn_s_setprio(0);
    }
  }

  u16* ob0 = opart + ((size_t)((sp*H + head)*N) + r0)*D;
  u16* ob1 = ob0 + (size_t)16*D;
  #pragma unroll
  for(int dt=0;dt<8;dt++){
    #pragma unroll
    for(int rg=0;rg<4;rg++){
      ob0[(size_t)(g4*4+rg)*D + dt*16 + l16] = f2bf(o0[dt][rg]);
      ob1[(size_t)(g4*4+rg)*D + dt*16 + l16] = f2bf(o1[dt][rg]);
    }
  }
  if(g4 == 0){
    mpart[(size_t)(sp*H + head)*N + r0 + l16]      = m0v;
    lpart[(size_t)(sp*H + head)*N + r0 + l16]      = ls0;
    mpart[(size_t)(sp*H + head)*N + r0 + 16 + l16] = m1v;
    lpart[(size_t)(sp*H + head)*N + r0 + 16 + l16] = ls1;
  }
}

// ---------------------------------------------------------------- launch
extern "C" void kernel_launch(void* const* d_in, const int* in_sizes, int n_in,
                              void* d_out, int out_size, void* d_ws, size_t ws_size,
                              hipStream_t stream){
  const float* x      = (const float*)d_in[0];
  const int*   ei     = (const int*)  d_in[1];
  const int*   spl    = (const int*)  d_in[2];
  const float* ef     = (const float*)d_in[3];
  const float* nodeW  = (const float*)d_in[4];
  const float* nodeb  = (const float*)d_in[5];
  const float* degemb = (const float*)d_in[6];
  const float* spe    = (const float*)d_in[7];
  const float* eW     = (const float*)d_in[8];
  const float* eb     = (const float*)d_in[9];
  const float* ln1g   = (const float*)d_in[10];
  const float* ln1b   = (const float*)d_in[11];
  const float* Wq     = (const float*)d_in[12];
  const float* bq     = (const float*)d_in[13];
  const float* Wk     = (const float*)d_in[14];
  const float* bk     = (const float*)d_in[15];
  const float* Wv     = (const float*)d_in[16];
  const float* bv     = (const float*)d_in[17];
  const float* Wo     = (const float*)d_in[18];
  const float* bo     = (const float*)d_in[19];
  const float* ln2g   = (const float*)d_in[20];
  const float* ln2b   = (const float*)d_in[21];
  const float* ffW    = (const float*)d_in[22];
  const float* ffb    = (const float*)d_in[23];
  const float* outW   = (const float*)d_in[24];
  const float* outb   = (const float*)d_in[25];

  constexpr size_t WT_ELEMS = 24*16384 + 2*16384 + 16384 + 2*65536;
  auto needed = [](int s)->size_t{
    size_t fl = 8192 + 3*(size_t)N*D;                                  // fp32 elems
    size_t bf = 3*(size_t)H*N*D + (size_t)N*N + (size_t)s*H*N*D;       // bf16 elems (incl opart)
    size_t pf = 2*(size_t)s*H*N;                                       // fp32 m/l
    return fl*4 + bf*2 + pf*4 + WT_ELEMS*2;
  };
  int S = 2;
  if(needed(8) <= ws_size) S = 8;
  else if(needed(4) <= ws_size) S = 4;

  float* ws   = (float*)d_ws;
  int*   deg  = (int*)ws;
  float* mask = ws + 4096;
  float* h    = ws + 8192;
  float* xln  = h    + N*D;
  float* xout = xln  + N*D;
  u16*   qb   = (u16*)(xout + N*D);
  u16*   kb   = qb + (size_t)H*N*D;
  u16*   vTb  = kb + (size_t)H*N*D;
  u16*   biasm= vTb + (size_t)H*N*D;
  u16*   opart= biasm + (size_t)N*N;            // S*H*N*D bf16
  float* mpart= (float*)(opart + (size_t)S*H*N*D);
  float* lpart= mpart + (size_t)S*H*N;
  u16*   wt_qkv = (u16*)(lpart + (size_t)S*H*N);
  u16*   wt_ff  = wt_qkv + 24*16384;
  u16*   wt_out = wt_ff  + 2*16384;
  u16*   wt_wo  = wt_out + 16384;

  k_wt_all<<<dim3(16, 27), 256, 0, stream>>>(Wq, Wk, Wv, ffW, outW, wt_qkv, wt_ff, wt_out);
  k_wt_wo<<<dim3(64, 2), 256, 0, stream>>>(Wo, wt_wo);
  k_zero_deg<<<(N+255)/256, 256, 0, stream>>>(deg);
  k_deg<<<(E+255)/256, 256, 0, stream>>>(ei, deg);
  k_h0<<<N, 64, 0, stream>>>(x, nodeW, nodeb, degemb, deg, ln1g, ln1b, mask, h, xln);
  k_bias<<<(N*N)/256, 256, 0, stream>>>(spl, ef, spe, eW, eb, mask, biasm);

  for(int l = 0; l < 2; ++l){
    k_mqkv<<<dim3(N/64, 12), 256, 0, stream>>>(xln, wt_qkv, bq, bk, bv, qb, kb, vTb, l);
    k_attn<<<dim3(N/128, H, S), 256, 0, stream>>>(qb, kb, vTb, biasm, opart, mpart, lpart, N/S);
    if(S == 8)
      k_mwo<8><<<N/64, 256, 0, stream>>>(opart, mpart, lpart, mask, wt_wo + (size_t)l*65536,
                                         bo + l*D, h, xout, xln, ln2g + l*D, ln2b + l*D);
    else if(S == 4)
      k_mwo<4><<<N/64, 256, 0, stream>>>(opart, mpart, lpart, mask, wt_wo + (size_t)l*65536,
                                         bo + l*D, h, xout, xln, ln2g + l*D, ln2b + l*D);
    else
      k_mwo<2><<<N/64, 256, 0, stream>>>(opart, mpart, lpart, mask, wt_wo + (size_t)l*65536,
                                         bo + l*D, h, xout, xln, ln2g + l*D, ln2b + l*D);
    k_mff<<<N/64, 256, 0, stream>>>(xln, wt_ff + (size_t)l*16384, ffb + l*D, xout, h, xln,
                                    ln1g + (l==0 ? D : 0), ln1b + (l==0 ? D : 0), l==0 ? 1 : 0);
  }
  k_mout<<<N/64, 256, 0, stream>>>(h, wt_out, outb, (float*)d_out);
}

// Round 11
// 219.306 us; speedup vs baseline: 1.2440x; 1.1246x over previous
//
#include <hip/hip_runtime.h>
#include <math.h>

static constexpr int N   = 3072;
static constexpr int DIN = 64;
static constexpr int D   = 128;
static constexpr int H   = 4;
static constexpr int E   = 49152;
#define NEGV  (-4294967295.0f)
#define SCALE (0.08838834764831845f)   // 1/sqrt(128)

typedef unsigned short u16;
typedef __attribute__((ext_vector_type(8))) short short8;
typedef __attribute__((ext_vector_type(4))) float f32x4;
typedef __attribute__((ext_vector_type(4))) unsigned short u16x4;

__device__ __forceinline__ u16 f2bf(float f){           // RNE float->bf16
  unsigned int u = __float_as_uint(f);
  u += 0x7fff + ((u >> 16) & 1);
  return (u16)(u >> 16);
}
__device__ __forceinline__ float bf2f(u16 u){
  return __uint_as_float(((unsigned int)u) << 16);
}

// ---------------------------------------------------------------- deg
__global__ void k_zero_deg(int* __restrict__ deg){
  int i = blockIdx.x*blockDim.x + threadIdx.x;
  if(i < N) deg[i] = 0;
}

__global__ void k_deg(const int* __restrict__ ei, int* __restrict__ deg){
  int e = blockIdx.x*blockDim.x + threadIdx.x;
  if(e < E) atomicAdd(&deg[ei[E + e]], 1);
}

// ---------------------------------------------------------------- h0 + fused LN1(layer0)
__global__ void k_h0(const float* __restrict__ x, const float* __restrict__ nodeW,
                     const float* __restrict__ nodeb, const float* __restrict__ degemb,
                     const int* __restrict__ deg, const float* __restrict__ g1,
                     const float* __restrict__ b1, float* __restrict__ mask,
                     float* __restrict__ h, float* __restrict__ xln){
  const int i = blockIdx.x, t = threadIdx.x;
  float xv = x[i*DIN + t];
  float s = xv;
  #pragma unroll
  for(int o=32;o;o>>=1) s += __shfl_xor(s, o);
  if(t == 0) mask[i] = (s != 0.0f) ? 1.0f : 0.0f;
  __shared__ float xr[DIN];
  xr[t] = xv;
  __syncthreads();
  int dg = deg[i]; dg = dg > N-1 ? N-1 : dg;
  float a0 = nodeb[t]      + degemb[dg*D + t];
  float a1 = nodeb[t + 64] + degemb[dg*D + t + 64];
  #pragma unroll
  for(int u=0; u<DIN; ++u){
    float xu = xr[u];
    a0 = fmaf(xu, nodeW[u*D + t],      a0);
    a1 = fmaf(xu, nodeW[u*D + t + 64], a1);
  }
  h[i*D + t]      = a0;
  h[i*D + t + 64] = a1;
  float s2 = a0 + a1, sq = a0*a0 + a1*a1;
  #pragma unroll
  for(int o=32;o;o>>=1){ s2 += __shfl_xor(s2, o); sq += __shfl_xor(sq, o); }
  float mean = s2*(1.0f/128.0f);
  float var  = sq*(1.0f/128.0f) - mean*mean;
  float inv  = rsqrtf(var + 1e-5f);
  xln[i*D + t]      = (a0 - mean)*inv*g1[t]      + b1[t];
  xln[i*D + t + 64] = (a1 - mean)*inv*g1[t + 64] + b1[t + 64];
}

// ---------------------------------------------------------------- bias (masked, bf16)
__global__ void k_bias(const int* __restrict__ spl, const float* __restrict__ ef,
                       const float* __restrict__ spe, const float* __restrict__ eW,
                       const float* __restrict__ eb, const float* __restrict__ mask,
                       u16* __restrict__ biasm){
  int idx = blockIdx.x*blockDim.x + threadIdx.x;   // < N*N
  int i = idx / N, j = idx % N;
  float wm0 = (eW[0] + eW[1] + eW[2] + eW[3])  * 0.25f;
  float wm1 = (eW[4] + eW[5] + eW[6] + eW[7])  * 0.25f;
  float wm2 = (eW[8] + eW[9] + eW[10]+ eW[11]) * 0.25f;
  float wm3 = (eW[12]+ eW[13]+ eW[14]+ eW[15]) * 0.25f;
  float bm  = (eb[0] + eb[1] + eb[2] + eb[3])  * 0.25f;
  float4 e4 = reinterpret_cast<const float4*>(ef)[idx];
  float em = fmaf(e4.x, wm0, fmaf(e4.y, wm1, fmaf(e4.z, wm2, fmaf(e4.w, wm3, bm))));
  float b = spe[spl[idx]] + em;
  float mk = mask[i]*mask[j];
  biasm[idx] = f2bf((mk != 0.0f) ? b : NEGV);
}

// ---------------------------------------------------------------- weight prep: fp32 [K][128] -> bf16 Bt [128][K]
__global__ __launch_bounds__(256) void k_wt_all(const float* __restrict__ Wq, const float* __restrict__ Wk,
    const float* __restrict__ Wv, const float* __restrict__ ffW, const float* __restrict__ outW,
    u16* __restrict__ wt_qkv, u16* __restrict__ wt_ff, u16* __restrict__ wt_out){
  __shared__ float t[32][33];
  const int z = blockIdx.y;
  const float* src; u16* dst;
  if(z < 24){
    int l = z/12, r = z%12;
    const float* W = (r>>2)==0 ? Wq : (r>>2)==1 ? Wk : Wv;
    src = W + (size_t)(l*4 + (r&3))*16384;
    dst = wt_qkv + (size_t)z*16384;
  } else if(z < 26){
    src = ffW + (size_t)(z-24)*16384; dst = wt_ff + (size_t)(z-24)*16384;
  } else { src = outW; dst = wt_out; }
  const int ki = blockIdx.x & 3, ni = blockIdx.x >> 2;
  const int tid = threadIdx.x;
  #pragma unroll
  for(int i=0;i<4;i++){
    int idx = tid + i*256, r = idx>>5, c = idx&31;
    t[r][c] = src[(size_t)(ki*32+r)*128 + ni*32 + c];
  }
  __syncthreads();
  #pragma unroll
  for(int i=0;i<4;i++){
    int idx = tid + i*256, r = idx>>5, c = idx&31;
    dst[(size_t)(ni*32+r)*128 + ki*32 + c] = f2bf(t[c][r]);
  }
}

__global__ __launch_bounds__(256) void k_wt_wo(const float* __restrict__ Wo, u16* __restrict__ wt_wo){
  __shared__ float t[32][33];
  const int l = blockIdx.y;
  const float* src = Wo + (size_t)l*65536;
  u16* dst = wt_wo + (size_t)l*65536;
  const int ki = blockIdx.x & 15, ni = blockIdx.x >> 4;
  const int tid = threadIdx.x;
  #pragma unroll
  for(int i=0;i<4;i++){
    int idx = tid + i*256, r = idx>>5, c = idx&31;
    t[r][c] = src[(size_t)(ki*32+r)*128 + ni*32 + c];
  }
  __syncthreads();
  #pragma unroll
  for(int i=0;i<4;i++){
    int idx = tid + i*256, r = idx>>5, c = idx&31;
    dst[(size_t)(ni*32+r)*512 + ki*32 + c] = f2bf(t[c][r]);
  }
}

// ---------------------------------------------------------------- bf16 MFMA GEMM (K=128), C = A@Bt^T + bias
// MODE: 1 = bf16 row-major, 2 = bf16 transposed (vT[d][n], coalesced via LDS)
template<int MODE>
__device__ __forceinline__ void mgemm_body(const float* __restrict__ A, const u16* __restrict__ Bt,
                                           const float* __restrict__ bias, void* __restrict__ Cv){
  __shared__ u16 As[64*128];
  __shared__ u16 Bs[128*128];
  const int tid = threadIdx.x, w = tid>>6, lane = tid&63;
  const int g4 = lane>>4, l16 = lane&15;
  const int m0 = blockIdx.x*64;
  const int srow = tid>>4, sch = tid&15;
  f32x4 acc[8];
  #pragma unroll
  for(int nt=0;nt<8;++nt) acc[nt] = (f32x4){0.f,0.f,0.f,0.f};
  #pragma unroll
  for(int it=0;it<4;++it){
    int row = it*16 + srow;
    const float4* ap = reinterpret_cast<const float4*>(A + (size_t)(m0+row)*128 + sch*8);
    float4 x0 = ap[0], x1 = ap[1];
    u16x4 p0, p1;
    p0.x=f2bf(x0.x); p0.y=f2bf(x0.y); p0.z=f2bf(x0.z); p0.w=f2bf(x0.w);
    p1.x=f2bf(x1.x); p1.y=f2bf(x1.y); p1.z=f2bf(x1.z); p1.w=f2bf(x1.w);
    u16* dst = &As[row*128 + ((sch ^ (row&15))*8)];
    *reinterpret_cast<u16x4*>(dst)     = p0;
    *reinterpret_cast<u16x4*>(dst + 4) = p1;
  }
  #pragma unroll
  for(int it=0;it<8;++it){
    int row = it*16 + srow;
    short8 b = *reinterpret_cast<const short8*>(Bt + (size_t)row*128 + sch*8);
    *reinterpret_cast<short8*>(&Bs[row*128 + ((sch ^ (row&15))*8)]) = b;
  }
  __syncthreads();
  __builtin_amdgcn_s_setprio(1);
  #pragma unroll
  for(int c=0;c<4;++c){
    short8 af = *reinterpret_cast<const short8*>(&As[(w*16+l16)*128 + (((c*4+g4) ^ l16)*8)]);
    #pragma unroll
    for(int nt=0;nt<8;++nt){
      short8 bf = *reinterpret_cast<const short8*>(&Bs[(nt*16+l16)*128 + (((c*4+g4) ^ l16)*8)]);
      acc[nt] = __builtin_amdgcn_mfma_f32_16x16x32_bf16(af, bf, acc[nt], 0, 0, 0);
    }
  }
  __builtin_amdgcn_s_setprio(0);
  const int mrow = m0 + w*16 + g4*4;
  if(MODE == 2){
    __syncthreads();
    u16* T = Bs;                                   // [col][64 rows], stride 68
    #pragma unroll
    for(int nt=0;nt<8;++nt){
      const int col = nt*16 + l16;
      float bi = bias[col];
      u16x4 t;
      t.x = f2bf(acc[nt][0] + bi); t.y = f2bf(acc[nt][1] + bi);
      t.z = f2bf(acc[nt][2] + bi); t.w = f2bf(acc[nt][3] + bi);
      *reinterpret_cast<u16x4*>(&T[col*68 + (w*16 + g4*4)]) = t;
    }
    __syncthreads();
    #pragma unroll
    for(int i=0;i<4;++i){
      int slot = tid + i*256;
      int col = slot >> 3, q = slot & 7;
      short8 v = *reinterpret_cast<const short8*>(&T[col*68 + q*8]);
      *reinterpret_cast<short8*>((u16*)Cv + (size_t)col*N + m0 + q*8) = v;
    }
  } else {
    #pragma unroll
    for(int nt=0;nt<8;++nt){
      const int col = nt*16 + l16;
      float bi = bias[col];
      #pragma unroll
      for(int rg=0;rg<4;++rg){
        float v = acc[nt][rg] + bi;
        ((u16*)Cv)[(size_t)(mrow+rg)*128 + col] = f2bf(v);
      }
    }
  }
}

// grid (N/64, 12): z = which*4 + head. V written directly transposed (vT[h][d][n]).
__global__ __launch_bounds__(256) void k_mqkv(const float* __restrict__ xln, const u16* __restrict__ wt_qkv,
    const float* __restrict__ bq, const float* __restrict__ bk, const float* __restrict__ bv,
    u16* __restrict__ q, u16* __restrict__ k, u16* __restrict__ vT, int l){
  const int z = blockIdx.y, which = z>>2, head = z&3;
  const u16* Bt = wt_qkv + (size_t)(l*12 + z)*16384;
  if(which == 0)      mgemm_body<1>(xln, Bt, bq + (l*H+head)*D, q  + (size_t)head*N*D);
  else if(which == 1) mgemm_body<1>(xln, Bt, bk + (l*H+head)*D, k  + (size_t)head*N*D);
  else                mgemm_body<2>(xln, Bt, bv + (l*H+head)*D, vT + (size_t)head*N*D);
}

// ---------------------------------------------------------------- fused Wo(+combine+LN2) + FF(+res) [+ out-proj]
// One block = 64 rows. GEMM1: Wo K=512 with split-K combine staging (bf16 partials).
// Epilogue1 in regs: xout = acc+bo+hres, LN2 -> stage xln to LDS -> GEMM2 (ffW).
// h = acc2+ffb+xout. !LAST: write h + LN1(l+1) xln. LAST: stage h -> GEMM3 (outW) -> d_out.
template<int S, bool LAST>
__global__ __launch_bounds__(256) void k_mwoff(const u16* __restrict__ opart, const float* __restrict__ mpart,
    const float* __restrict__ lpart, const float* __restrict__ mask, const u16* __restrict__ wt_wo_l,
    const float* __restrict__ bo_l, const float* __restrict__ hres,
    const u16* __restrict__ wt_ff_l, const float* __restrict__ ffb_l,
    const float* __restrict__ g2, const float* __restrict__ b2,
    float* __restrict__ hout, float* __restrict__ xlnout,
    const float* __restrict__ g1n, const float* __restrict__ b1n,
    const u16* __restrict__ wt_out_m, const float* __restrict__ outb_m,
    float* __restrict__ finalout){
  __shared__ u16 As[64*128];
  __shared__ u16 Bs[128*128];
  const int tid = threadIdx.x, w = tid>>6, lane = tid&63;
  const int g4 = lane>>4, l16 = lane&15;
  const int m0 = blockIdx.x*64;
  const int srow = tid>>4, sch = tid&15;
  f32x4 acc[8];
  #pragma unroll
  for(int nt=0;nt<8;++nt) acc[nt] = (f32x4){0.f,0.f,0.f,0.f};
  // ---- GEMM1: Wo (K=512), A built by split-K combine
  for(int k0 = 0; k0 < 512; k0 += 128){
    const int hh = k0 >> 7;
    __syncthreads();
    #pragma unroll
    for(int it=0;it<4;++it){
      int row = it*16 + srow;
      int grow = m0 + row;
      float w_[S]; float M = -INFINITY; float mv[S], lv[S];
      #pragma unroll
      for(int s=0;s<S;++s){
        mv[s] = mpart[(size_t)(s*H + hh)*N + grow];
        lv[s] = lpart[(size_t)(s*H + hh)*N + grow];
        M = fmaxf(M, mv[s]);
      }
      float denom = 0.f;
      #pragma unroll
      for(int s=0;s<S;++s){ w_[s] = __expf(mv[s] - M); denom = fmaf(lv[s], w_[s], denom); }
      float scale = mask[grow] / denom;
      const int d = sch*8;
      float v[8] = {0,0,0,0,0,0,0,0};
      #pragma unroll
      for(int s=0;s<S;++s){
        short8 ov = *reinterpret_cast<const short8*>(
            opart + ((size_t)(s*H + hh)*N + grow)*D + d);
        #pragma unroll
        for(int j=0;j<8;++j) v[j] = fmaf(bf2f((u16)ov[j]), w_[s], v[j]);
      }
      u16x4 p0, p1;
      p0.x=f2bf(v[0]*scale); p0.y=f2bf(v[1]*scale); p0.z=f2bf(v[2]*scale); p0.w=f2bf(v[3]*scale);
      p1.x=f2bf(v[4]*scale); p1.y=f2bf(v[5]*scale); p1.z=f2bf(v[6]*scale); p1.w=f2bf(v[7]*scale);
      u16* dst = &As[row*128 + ((sch ^ (row&15))*8)];
      *reinterpret_cast<u16x4*>(dst)     = p0;
      *reinterpret_cast<u16x4*>(dst + 4) = p1;
    }
    #pragma unroll
    for(int it=0;it<8;++it){
      int row = it*16 + srow;
      short8 b = *reinterpret_cast<const short8*>(wt_wo_l + (size_t)row*512 + k0 + sch*8);
      *reinterpret_cast<short8*>(&Bs[row*128 + ((sch ^ (row&15))*8)]) = b;
    }
    __syncthreads();
    __builtin_amdgcn_s_setprio(1);
    #pragma unroll
    for(int c=0;c<4;++c){
      short8 af = *reinterpret_cast<const short8*>(&As[(w*16+l16)*128 + (((c*4+g4) ^ l16)*8)]);
      #pragma unroll
      for(int nt=0;nt<8;++nt){
        short8 bf = *reinterpret_cast<const short8*>(&Bs[(nt*16+l16)*128 + (((c*4+g4) ^ l16)*8)]);
        acc[nt] = __builtin_amdgcn_mfma_f32_16x16x32_bf16(af, bf, acc[nt], 0, 0, 0);
      }
    }
    __builtin_amdgcn_s_setprio(0);
  }
  const int mrow = m0 + w*16 + g4*4;
  // ---- epilogue1: xout = acc + bo + hres (kept in acc), LN2 stats
  float s_[4] = {0,0,0,0}, q_[4] = {0,0,0,0};
  #pragma unroll
  for(int nt=0;nt<8;++nt){
    const int col = nt*16 + l16;
    float bi = bo_l[col];
    #pragma unroll
    for(int rg=0;rg<4;++rg){
      float v = acc[nt][rg] + bi + hres[(size_t)(mrow+rg)*128 + col];
      acc[nt][rg] = v;
      s_[rg] += v; q_[rg] = fmaf(v, v, q_[rg]);
    }
  }
  #pragma unroll
  for(int o=1;o<16;o<<=1){
    #pragma unroll
    for(int rg=0;rg<4;++rg){ s_[rg] += __shfl_xor(s_[rg], o); q_[rg] += __shfl_xor(q_[rg], o); }
  }
  float mean[4], inv[4];
  #pragma unroll
  for(int rg=0;rg<4;++rg){
    mean[rg] = s_[rg]*(1.0f/128.0f);
    float var = q_[rg]*(1.0f/128.0f) - mean[rg]*mean[rg];
    inv[rg] = rsqrtf(var + 1e-5f);
  }
  // ---- stage LN2(xout) into As + wt_ff into Bs
  __syncthreads();                                 // all waves done with GEMM1's As/Bs
  #pragma unroll
  for(int nt=0;nt<8;++nt){
    const int col = nt*16 + l16;
    const int ch = col >> 3, wi = col & 7;
    float gg = g2[col], bb = b2[col];
    #pragma unroll
    for(int rg=0;rg<4;++rg){
      int row = w*16 + g4*4 + rg;
      As[row*128 + ((ch ^ (row&15))*8) + wi] = f2bf((acc[nt][rg] - mean[rg])*inv[rg]*gg + bb);
    }
  }
  #pragma unroll
  for(int it=0;it<8;++it){
    int row = it*16 + srow;
    short8 b = *reinterpret_cast<const short8*>(wt_ff_l + (size_t)row*128 + sch*8);
    *reinterpret_cast<short8*>(&Bs[row*128 + ((sch ^ (row&15))*8)]) = b;
  }
  __syncthreads();
  // ---- GEMM2: FF
  f32x4 acc2[8];
  #pragma unroll
  for(int nt=0;nt<8;++nt) acc2[nt] = (f32x4){0.f,0.f,0.f,0.f};
  __builtin_amdgcn_s_setprio(1);
  #pragma unroll
  for(int c=0;c<4;++c){
    short8 af = *reinterpret_cast<const short8*>(&As[(w*16+l16)*128 + (((c*4+g4) ^ l16)*8)]);
    #pragma unroll
    for(int nt=0;nt<8;++nt){
      short8 bf = *reinterpret_cast<const short8*>(&Bs[(nt*16+l16)*128 + (((c*4+g4) ^ l16)*8)]);
      acc2[nt] = __builtin_amdgcn_mfma_f32_16x16x32_bf16(af, bf, acc2[nt], 0, 0, 0);
    }
  }
  __builtin_amdgcn_s_setprio(0);
  // h = acc2 + ffb + xout(acc)
  #pragma unroll
  for(int nt=0;nt<8;++nt){
    const int col = nt*16 + l16;
    float bi = ffb_l[col];
    #pragma unroll
    for(int rg=0;rg<4;++rg)
      acc2[nt][rg] += bi + acc[nt][rg];
  }
  if(!LAST){
    // write h + LN1(l+1)
    float s2_[4] = {0,0,0,0}, q2_[4] = {0,0,0,0};
    #pragma unroll
    for(int nt=0;nt<8;++nt){
      const int col = nt*16 + l16;
      #pragma unroll
      for(int rg=0;rg<4;++rg){
        float v = acc2[nt][rg];
        hout[(size_t)(mrow+rg)*128 + col] = v;
        s2_[rg] += v; q2_[rg] = fmaf(v, v, q2_[rg]);
      }
    }
    #pragma unroll
    for(int o=1;o<16;o<<=1){
      #pragma unroll
      for(int rg=0;rg<4;++rg){ s2_[rg] += __shfl_xor(s2_[rg], o); q2_[rg] += __shfl_xor(q2_[rg], o); }
    }
    #pragma unroll
    for(int rg=0;rg<4;++rg){
      float mn = s2_[rg]*(1.0f/128.0f);
      float var = q2_[rg]*(1.0f/128.0f) - mn*mn;
      s2_[rg] = mn; q2_[rg] = rsqrtf(var + 1e-5f);
    }
    #pragma unroll
    for(int nt=0;nt<8;++nt){
      const int col = nt*16 + l16;
      float gg = g1n[col], bb = b1n[col];
      #pragma unroll
      for(int rg=0;rg<4;++rg)
        xlnout[(size_t)(mrow+rg)*128 + col] = (acc2[nt][rg] - s2_[rg])*q2_[rg]*gg + bb;
    }
  } else {
    // ---- GEMM3: out-proj. stage h into As, wt_out into Bs
    __syncthreads();
    #pragma unroll
    for(int nt=0;nt<8;++nt){
      const int col = nt*16 + l16;
      const int ch = col >> 3, wi = col & 7;
      #pragma unroll
      for(int rg=0;rg<4;++rg){
        int row = w*16 + g4*4 + rg;
        As[row*128 + ((ch ^ (row&15))*8) + wi] = f2bf(acc2[nt][rg]);
      }
    }
    #pragma unroll
    for(int it=0;it<8;++it){
      int row = it*16 + srow;
      short8 b = *reinterpret_cast<const short8*>(wt_out_m + (size_t)row*128 + sch*8);
      *reinterpret_cast<short8*>(&Bs[row*128 + ((sch ^ (row&15))*8)]) = b;
    }
    __syncthreads();
    f32x4 acc3[8];
    #pragma unroll
    for(int nt=0;nt<8;++nt) acc3[nt] = (f32x4){0.f,0.f,0.f,0.f};
    __builtin_amdgcn_s_setprio(1);
    #pragma unroll
    for(int c=0;c<4;++c){
      short8 af = *reinterpret_cast<const short8*>(&As[(w*16+l16)*128 + (((c*4+g4) ^ l16)*8)]);
      #pragma unroll
      for(int nt=0;nt<8;++nt){
        short8 bf = *reinterpret_cast<const short8*>(&Bs[(nt*16+l16)*128 + (((c*4+g4) ^ l16)*8)]);
        acc3[nt] = __builtin_amdgcn_mfma_f32_16x16x32_bf16(af, bf, acc3[nt], 0, 0, 0);
      }
    }
    __builtin_amdgcn_s_setprio(0);
    #pragma unroll
    for(int nt=0;nt<8;++nt){
      const int col = nt*16 + l16;
      float bi = outb_m[col];
      #pragma unroll
      for(int rg=0;rg<4;++rg)
        finalout[(size_t)(mrow+rg)*128 + col] = acc3[nt][rg] + bi;
    }
  }
}

// ---------------------------------------------------------------- MFMA flash attention, LDS-staged K/V (R8 body, bf16 opart)
__global__ __launch_bounds__(256) void k_attn(const u16* __restrict__ q, const u16* __restrict__ k,
                     const u16* __restrict__ vT, const u16* __restrict__ biasm,
                     u16* __restrict__ opart, float* __restrict__ mpart, float* __restrict__ lpart,
                     int kvlen){
  const int tid  = threadIdx.x;
  const int w    = tid >> 6;
  const int lane = tid & 63;
  const int g4 = lane >> 4, l16 = lane & 15;
  const int head = blockIdx.y, sp = blockIdx.z;
  const int r0 = blockIdx.x*64 + w*16;
  __shared__ u16 Ks[64*128];          // [key][128 dims], swizzled
  __shared__ u16 Vs[64*128];          // [d&63][seg | 64 keys], swizzled
  __shared__ u16 P[4][16][40];        // per-wave P, padded stride

  const u16* qbase = q + ((size_t)head*N + r0)*D;
  short8 qf[4];
  #pragma unroll
  for(int c=0;c<4;c++)
    qf[c] = *reinterpret_cast<const short8*>(qbase + l16*D + c*32 + g4*8);

  f32x4 o[8];
  #pragma unroll
  for(int dt=0;dt<8;dt++) o[dt] = (f32x4){0.f,0.f,0.f,0.f};
  float m = -INFINITY, lsum = 0.0f;

  const u16* kh   = k  + (size_t)head*N*D;
  const u16* vTh  = vT + (size_t)head*D*N;
  const u16* brow = biasm + (size_t)(r0 + l16)*N;
  const int kv0 = sp*kvlen;

  const int krow = tid >> 4, kch = tid & 15;
  const int vrow = tid >> 3, vch = tid & 7;

  for(int j0 = kv0; j0 < kv0 + kvlen; j0 += 64){
    short8 kreg[4], vreg[4];
    #pragma unroll
    for(int it=0; it<4; ++it)
      kreg[it] = *reinterpret_cast<const short8*>(kh + (size_t)(j0 + it*16 + krow)*D + kch*8);
    #pragma unroll
    for(int it=0; it<4; ++it)
      vreg[it] = *reinterpret_cast<const short8*>(vTh + (size_t)(it*32 + vrow)*N + j0 + vch*8);
    u16x4 bb[4];
    #pragma unroll
    for(int z=0; z<4; ++z)
      bb[z] = *reinterpret_cast<const u16x4*>(brow + j0 + z*16 + g4*4);

    __syncthreads();
    #pragma unroll
    for(int it=0; it<4; ++it){
      int row = it*16 + krow;
      *reinterpret_cast<short8*>(&Ks[row*128 + ((kch ^ (row&15))*8)]) = kreg[it];
    }
    #pragma unroll
    for(int it=0; it<4; ++it){
      int d = it*32 + vrow;
      int row = d & 63, ch = ((d>>6)<<3) | vch;
      *reinterpret_cast<short8*>(&Vs[row*128 + ((ch ^ (row&15))*8)]) = vreg[it];
    }
    __syncthreads();

    #pragma unroll
    for(int ks=0; ks<2; ++ks){
      short8 kf[8];
      const int rowA = ks*32 + l16, rowB = rowA + 16;
      #pragma unroll
      for(int c=0;c<4;c++){
        kf[c]   = *reinterpret_cast<const short8*>(&Ks[rowA*128 + (((c*4+g4) ^ l16)*8)]);
        kf[4+c] = *reinterpret_cast<const short8*>(&Ks[rowB*128 + (((c*4+g4) ^ l16)*8)]);
      }
      f32x4 sA = (f32x4){0.f,0.f,0.f,0.f}, sB = sA;
      __builtin_amdgcn_s_setprio(1);
      #pragma unroll
      for(int c=0;c<4;c++){
        sA = __builtin_amdgcn_mfma_f32_16x16x32_bf16(kf[c],   qf[c], sA, 0, 0, 0);
        sB = __builtin_amdgcn_mfma_f32_16x16x32_bf16(kf[4+c], qf[c], sB, 0, 0, 0);
      }
      __builtin_amdgcn_s_setprio(0);
      u16x4 bA = bb[2*ks], bB = bb[2*ks+1];
      sA[0] = fmaf(sA[0], SCALE, bf2f(bA.x)); sA[1] = fmaf(sA[1], SCALE, bf2f(bA.y));
      sA[2] = fmaf(sA[2], SCALE, bf2f(bA.z)); sA[3] = fmaf(sA[3], SCALE, bf2f(bA.w));
      sB[0] = fmaf(sB[0], SCALE, bf2f(bB.x)); sB[1] = fmaf(sB[1], SCALE, bf2f(bB.y));
      sB[2] = fmaf(sB[2], SCALE, bf2f(bB.z)); sB[3] = fmaf(sB[3], SCALE, bf2f(bB.w));
      float pmax = fmaxf(fmaxf(fmaxf(sA[0],sA[1]), fmaxf(sA[2],sA[3])),
                         fmaxf(fmaxf(sB[0],sB[1]), fmaxf(sB[2],sB[3])));
      pmax = fmaxf(pmax, __shfl_xor(pmax, 16));
      pmax = fmaxf(pmax, __shfl_xor(pmax, 32));
      if(!__all(pmax - m <= 8.0f)){
        float mnew = fmaxf(m, pmax);
        float corr = __expf(m - mnew);
        lsum *= corr;
        float c0 = __shfl(corr, (lane & 48) | (g4*4 + 0));
        float c1 = __shfl(corr, (lane & 48) | (g4*4 + 1));
        float c2 = __shfl(corr, (lane & 48) | (g4*4 + 2));
        float c3 = __shfl(corr, (lane & 48) | (g4*4 + 3));
        #pragma unroll
        for(int dt=0;dt<8;dt++){
          o[dt][0] *= c0; o[dt][1] *= c1; o[dt][2] *= c2; o[dt][3] *= c3;
        }
        m = mnew;
      }
      f32x4 pA, pB;
      #pragma unroll
      for(int rg=0;rg<4;rg++){ pA[rg] = __expf(sA[rg] - m); pB[rg] = __expf(sB[rg] - m); }
      float ps = (pA[0]+pA[1]) + (pA[2]+pA[3]) + ((pB[0]+pB[1]) + (pB[2]+pB[3]));
      ps += __shfl_xor(ps, 16);
      ps += __shfl_xor(ps, 32);
      lsum += ps;
      u16x4 wa, wb;
      wa.x = f2bf(pA[0]); wa.y = f2bf(pA[1]); wa.z = f2bf(pA[2]); wa.w = f2bf(pA[3]);
      wb.x = f2bf(pB[0]); wb.y = f2bf(pB[1]); wb.z = f2bf(pB[2]); wb.w = f2bf(pB[3]);
      *reinterpret_cast<u16x4*>(&P[w][l16][g4*4])      = wa;
      *reinterpret_cast<u16x4*>(&P[w][l16][16 + g4*4]) = wb;
      short8 pf = *reinterpret_cast<const short8*>(&P[w][l16][g4*8]);
      __builtin_amdgcn_s_setprio(1);
      #pragma unroll
      for(int dt=0;dt<8;dt++){
        int d = dt*16 + l16;
        int row = d & 63;
        int ch  = ((dt>>2)<<3) | (ks<<2) | g4;
        short8 vf = *reinterpret_cast<const short8*>(&Vs[row*128 + ((ch ^ l16)*8)]);
        o[dt] = __builtin_amdgcn_mfma_f32_16x16x32_bf16(pf, vf, o[dt], 0, 0, 0);
      }
      __builtin_amdgcn_s_setprio(0);
    }
  }

  u16* ob = opart + ((size_t)((sp*H + head)*N) + r0)*D;
  #pragma unroll
  for(int dt=0;dt<8;dt++){
    #pragma unroll
    for(int rg=0;rg<4;rg++)
      ob[(size_t)(g4*4+rg)*D + dt*16 + l16] = f2bf(o[dt][rg]);
  }
  if(g4 == 0){
    mpart[(size_t)(sp*H + head)*N + r0 + l16] = m;
    lpart[(size_t)(sp*H + head)*N + r0 + l16] = lsum;
  }
}

// ---------------------------------------------------------------- launch
extern "C" void kernel_launch(void* const* d_in, const int* in_sizes, int n_in,
                              void* d_out, int out_size, void* d_ws, size_t ws_size,
                              hipStream_t stream){
  const float* x      = (const float*)d_in[0];
  const int*   ei     = (const int*)  d_in[1];
  const int*   spl    = (const int*)  d_in[2];
  const float* ef     = (const float*)d_in[3];
  const float* nodeW  = (const float*)d_in[4];
  const float* nodeb  = (const float*)d_in[5];
  const float* degemb = (const float*)d_in[6];
  const float* spe    = (const float*)d_in[7];
  const float* eW     = (const float*)d_in[8];
  const float* eb     = (const float*)d_in[9];
  const float* ln1g   = (const float*)d_in[10];
  const float* ln1b   = (const float*)d_in[11];
  const float* Wq     = (const float*)d_in[12];
  const float* bq     = (const float*)d_in[13];
  const float* Wk     = (const float*)d_in[14];
  const float* bk     = (const float*)d_in[15];
  const float* Wv     = (const float*)d_in[16];
  const float* bv     = (const float*)d_in[17];
  const float* Wo     = (const float*)d_in[18];
  const float* bo     = (const float*)d_in[19];
  const float* ln2g   = (const float*)d_in[20];
  const float* ln2b   = (const float*)d_in[21];
  const float* ffW    = (const float*)d_in[22];
  const float* ffb    = (const float*)d_in[23];
  const float* outW   = (const float*)d_in[24];
  const float* outb   = (const float*)d_in[25];

  constexpr size_t WT_ELEMS = 24*16384 + 2*16384 + 16384 + 2*65536;
  auto needed = [](int s)->size_t{
    size_t fl = 8192 + 3*(size_t)N*D;
    size_t bf = 3*(size_t)H*N*D + (size_t)N*N + (size_t)s*H*N*D;
    size_t pf = 2*(size_t)s*H*N;
    return fl*4 + bf*2 + pf*4 + WT_ELEMS*2;
  };
  int S = 2;
  if(needed(8) <= ws_size) S = 8;
  else if(needed(4) <= ws_size) S = 4;

  float* ws   = (float*)d_ws;
  int*   deg  = (int*)ws;
  float* mask = ws + 4096;
  float* h    = ws + 8192;
  float* xln  = h    + N*D;
  float* xout = xln  + N*D;          // unused (kept for layout stability)
  u16*   qb   = (u16*)(xout + N*D);
  u16*   kb   = qb + (size_t)H*N*D;
  u16*   vTb  = kb + (size_t)H*N*D;
  u16*   biasm= vTb + (size_t)H*N*D;
  u16*   opart= biasm + (size_t)N*N;            // S*H*N*D bf16
  float* mpart= (float*)(opart + (size_t)S*H*N*D);
  float* lpart= mpart + (size_t)S*H*N;
  u16*   wt_qkv = (u16*)(lpart + (size_t)S*H*N);
  u16*   wt_ff  = wt_qkv + 24*16384;
  u16*   wt_out = wt_ff  + 2*16384;
  u16*   wt_wo  = wt_out + 16384;

  k_wt_all<<<dim3(16, 27), 256, 0, stream>>>(Wq, Wk, Wv, ffW, outW, wt_qkv, wt_ff, wt_out);
  k_wt_wo<<<dim3(64, 2), 256, 0, stream>>>(Wo, wt_wo);
  k_zero_deg<<<(N+255)/256, 256, 0, stream>>>(deg);
  k_deg<<<(E+255)/256, 256, 0, stream>>>(ei, deg);
  k_h0<<<N, 64, 0, stream>>>(x, nodeW, nodeb, degemb, deg, ln1g, ln1b, mask, h, xln);
  k_bias<<<(N*N)/256, 256, 0, stream>>>(spl, ef, spe, eW, eb, mask, biasm);

  for(int l = 0; l < 2; ++l){
    k_mqkv<<<dim3(N/64, 12), 256, 0, stream>>>(xln, wt_qkv, bq, bk, bv, qb, kb, vTb, l);
    k_attn<<<dim3(N/64, H, S), 256, 0, stream>>>(qb, kb, vTb, biasm, opart, mpart, lpart, N/S);
    const u16* wwo = wt_wo + (size_t)l*65536;
    const u16* wff = wt_ff + (size_t)l*16384;
    if(l == 0){
      if(S == 8)
        k_mwoff<8,false><<<N/64, 256, 0, stream>>>(opart, mpart, lpart, mask, wwo, bo + l*D, h,
            wff, ffb + l*D, ln2g + l*D, ln2b + l*D, h, xln, ln1g + D, ln1b + D,
            nullptr, nullptr, nullptr);
      else if(S == 4)
        k_mwoff<4,false><<<N/64, 256, 0, stream>>>(opart, mpart, lpart, mask, wwo, bo + l*D, h,
            wff, ffb + l*D, ln2g + l*D, ln2b + l*D, h, xln, ln1g + D, ln1b + D,
            nullptr, nullptr, nullptr);
      else
        k_mwoff<2,false><<<N/64, 256, 0, stream>>>(opart, mpart, lpart, mask, wwo, bo + l*D, h,
            wff, ffb + l*D, ln2g + l*D, ln2b + l*D, h, xln, ln1g + D, ln1b + D,
            nullptr, nullptr, nullptr);
    } else {
      if(S == 8)
        k_mwoff<8,true><<<N/64, 256, 0, stream>>>(opart, mpart, lpart, mask, wwo, bo + l*D, h,
            wff, ffb + l*D, ln2g + l*D, ln2b + l*D, nullptr, nullptr, nullptr, nullptr,
            wt_out, outb, (float*)d_out);
      else if(S == 4)
        k_mwoff<4,true><<<N/64, 256, 0, stream>>>(opart, mpart, lpart, mask, wwo, bo + l*D, h,
            wff, ffb + l*D, ln2g + l*D, ln2b + l*D, nullptr, nullptr, nullptr, nullptr,
            wt_out, outb, (float*)d_out);
      else
        k_mwoff<2,true><<<N/64, 256, 0, stream>>>(opart, mpart, lpart, mask, wwo, bo + l*D, h,
            wff, ffb + l*D, ln2g + l*D, ln2b + l*D, nullptr, nullptr, nullptr, nullptr,
            wt_out, outb, (float*)d_out);
    }
  }
}